// Round 2
// baseline (1062.915 us; speedup 1.0000x reference)
//
#include <hip/hip_runtime.h>
#include <math.h>

#ifndef M_PI
#define M_PI 3.14159265358979323846
#endif

// Problem constants
constexpr int  NB   = 8;
constexpr int  CH   = 256;
constexpr long HW   = 4096;                 // 64*64
constexpr long SLOT = (long)NB * CH * HW;   // floats per [8,256,64,64] tensor

// ---------------------------------------------------------------------------
// Tiled SGEMM:  C[b] (MxN) = A[b] (MxK) * B[b] (KxN)   (or B is [N,K] if BT)
// Tile 128(M) x 128(N), BK=16, 256 threads, 8x8 microtile per thread.
// EPI 0: bias (nullable) + store.  EPI 1: atomicAdd (split-K accumulate).
// EPI 2: cfr->mix fused epilogue: mix = beta*(cfr*(Q - lam*V) + V) + (1-beta)*Fw
// ---------------------------------------------------------------------------
template<bool BT, int EPI>
__global__ __launch_bounds__(256, 2)
void gemm_kernel(const float* __restrict__ A, const float* __restrict__ B,
                 float* __restrict__ C, const float* __restrict__ bias,
                 int M, int N, int K, int nSplitK,
                 long aStride, long bStride, long cStride,
                 const float* __restrict__ qb, const float* __restrict__ vb,
                 const float* __restrict__ fwb,
                 const float* __restrict__ lambd, const float* __restrict__ beta)
{
  __shared__ __align__(16) float As[16][132];   // [k][m]
  __shared__ __align__(16) float Bs[16][132];   // [k][n]
  const int tid = threadIdx.x;
  const int b   = blockIdx.z / nSplitK;
  const int ks  = blockIdx.z % nSplitK;
  const int kLen = K / nSplitK;
  const int k0b  = ks * kLen;
  const float* Ab = A + (long)b * aStride;
  const float* Bb = B + (long)b * bStride;
  float* Cb = C + (long)b * cStride;
  const int m0 = blockIdx.y * 128;
  const int n0 = blockIdx.x * 128;

  float acc[8][8];
#pragma unroll
  for (int i = 0; i < 8; ++i)
#pragma unroll
    for (int j = 0; j < 8; ++j) acc[i][j] = 0.f;

  const int tx = tid & 15;        // n octet
  const int ty = tid >> 4;        // m octet
  const int lr = tid >> 1;        // 0..127: A row (or B row for BT)
  const int lk = (tid & 1) * 8;   // k offset 0/8
  const int bn = (tid & 31) * 4;  // B col (!BT)
  const int bk = tid >> 5;        // 0..7   (!BT)

  for (int kt = 0; kt < kLen; kt += 16) {
    const int k0 = k0b + kt;
    {
      const float* ap = &Ab[(long)(m0 + lr) * K + k0 + lk];
      const float4 a0 = *(const float4*)ap;
      const float4 a1 = *(const float4*)(ap + 4);
      As[lk+0][lr] = a0.x; As[lk+1][lr] = a0.y; As[lk+2][lr] = a0.z; As[lk+3][lr] = a0.w;
      As[lk+4][lr] = a1.x; As[lk+5][lr] = a1.y; As[lk+6][lr] = a1.z; As[lk+7][lr] = a1.w;
    }
    if (BT) {
      const float* bp = &Bb[(long)(n0 + lr) * K + k0 + lk];
      const float4 b0 = *(const float4*)bp;
      const float4 b1 = *(const float4*)(bp + 4);
      Bs[lk+0][lr] = b0.x; Bs[lk+1][lr] = b0.y; Bs[lk+2][lr] = b0.z; Bs[lk+3][lr] = b0.w;
      Bs[lk+4][lr] = b1.x; Bs[lk+5][lr] = b1.y; Bs[lk+6][lr] = b1.z; Bs[lk+7][lr] = b1.w;
    } else {
      const float4 b0 = *(const float4*)&Bb[(long)(k0 + bk) * N + n0 + bn];
      const float4 b1 = *(const float4*)&Bb[(long)(k0 + bk + 8) * N + n0 + bn];
      *(float4*)&Bs[bk][bn]     = b0;
      *(float4*)&Bs[bk + 8][bn] = b1;
    }
    __syncthreads();
#pragma unroll
    for (int kk = 0; kk < 16; ++kk) {
      const float4 a0 = *(const float4*)&As[kk][ty * 8];
      const float4 a1 = *(const float4*)&As[kk][ty * 8 + 4];
      const float4 b0 = *(const float4*)&Bs[kk][tx * 8];
      const float4 b1 = *(const float4*)&Bs[kk][tx * 8 + 4];
      const float av[8] = {a0.x, a0.y, a0.z, a0.w, a1.x, a1.y, a1.z, a1.w};
      const float bv[8] = {b0.x, b0.y, b0.z, b0.w, b1.x, b1.y, b1.z, b1.w};
#pragma unroll
      for (int i = 0; i < 8; ++i)
#pragma unroll
        for (int j = 0; j < 8; ++j)
          acc[i][j] = fmaf(av[i], bv[j], acc[i][j]);
    }
    __syncthreads();
  }

  if (EPI == 0) {
#pragma unroll
    for (int i = 0; i < 8; ++i) {
      const int row = m0 + ty * 8 + i;
      const float bb = bias ? bias[row] : 0.f;
      float4 r0, r1;
      r0.x = acc[i][0] + bb; r0.y = acc[i][1] + bb; r0.z = acc[i][2] + bb; r0.w = acc[i][3] + bb;
      r1.x = acc[i][4] + bb; r1.y = acc[i][5] + bb; r1.z = acc[i][6] + bb; r1.w = acc[i][7] + bb;
      float* p = &Cb[(long)row * N + n0 + tx * 8];
      *(float4*)p       = r0;
      *(float4*)(p + 4) = r1;
    }
  } else if (EPI == 1) {
#pragma unroll
    for (int i = 0; i < 8; ++i) {
      const int row = m0 + ty * 8 + i;
      float* p = &Cb[(long)row * N + n0 + tx * 8];
#pragma unroll
      for (int j = 0; j < 8; ++j) atomicAdd(p + j, acc[i][j]);
    }
  } else {
    const float lam = lambd[0], bet = beta[0];
#pragma unroll
    for (int i = 0; i < 8; ++i) {
      const int row = m0 + ty * 8 + i;
      const long off = (long)row * N + n0 + tx * 8;
      const long gi  = (long)b * cStride + off;
      const float4 q0 = *(const float4*)&qb[gi],  q1 = *(const float4*)&qb[gi + 4];
      const float4 v0 = *(const float4*)&vb[gi],  v1 = *(const float4*)&vb[gi + 4];
      const float4 f0 = *(const float4*)&fwb[gi], f1 = *(const float4*)&fwb[gi + 4];
      const float qv[8] = {q0.x,q0.y,q0.z,q0.w,q1.x,q1.y,q1.z,q1.w};
      const float vv[8] = {v0.x,v0.y,v0.z,v0.w,v1.x,v1.y,v1.z,v1.w};
      const float fv[8] = {f0.x,f0.y,f0.z,f0.w,f1.x,f1.y,f1.z,f1.w};
      float r[8];
#pragma unroll
      for (int j = 0; j < 8; ++j)
        r[j] = bet * (acc[i][j] * (qv[j] - lam * vv[j]) + vv[j]) + (1.f - bet) * fv[j];
      float* p = &Cb[off];
      *(float4*)p       = make_float4(r[0], r[1], r[2], r[3]);
      *(float4*)(p + 4) = make_float4(r[4], r[5], r[6], r[7]);
    }
  }
}

// ---------------------------------------------------------------------------
// pooled[b,c] = mean over HW of (FR + FN)
// ---------------------------------------------------------------------------
__global__ __launch_bounds__(256)
void pool_kernel(const float* __restrict__ FR, const float* __restrict__ FN,
                 float* __restrict__ pooled)
{
  __shared__ float red[256];
  const int bc = blockIdx.x, tid = threadIdx.x;
  const float4* a = (const float4*)(FR + (long)bc * HW);
  const float4* b = (const float4*)(FN + (long)bc * HW);
  float s = 0.f;
  for (int v = tid; v < 1024; v += 256) {
    const float4 x = a[v]; s += x.x + x.y + x.z + x.w;
    const float4 y = b[v]; s += y.x + y.y + y.z + y.w;
  }
  red[tid] = s; __syncthreads();
  for (int o = 128; o > 0; o >>= 1) {
    if (tid < o) red[tid] += red[tid + o];
    __syncthreads();
  }
  if (tid == 0) pooled[bc] = red[0] * (1.f / 4096.f);
}

// ---------------------------------------------------------------------------
// MLP (relu) + 2-way softmax -> attn2 [8,2,256]
// ---------------------------------------------------------------------------
__global__ __launch_bounds__(256)
void attn2_kernel(const float* __restrict__ pooled, const float* __restrict__ w1,
                  const float* __restrict__ w2, float* __restrict__ attn2)
{
  __shared__ float ps[256];
  __shared__ float hs[32];
  const int b = blockIdx.x, tid = threadIdx.x;
  ps[tid] = pooled[b * 256 + tid];
  __syncthreads();
  if (tid < 32) {
    float a = 0.f;
    for (int c = 0; c < 256; ++c) a += ps[c] * w1[tid * 256 + c];
    hs[tid] = fmaxf(a, 0.f);
  }
  __syncthreads();
  float a0 = 0.f, a1 = 0.f;
  for (int d = 0; d < 32; ++d) {
    const float h = hs[d];
    a0 += h * w2[tid * 32 + d];
    a1 += h * w2[(256 + tid) * 32 + d];
  }
  const float m  = fmaxf(a0, a1);
  const float e0 = expf(a0 - m), e1 = expf(a1 - m);
  const float inv = 1.f / (e0 + e1);
  attn2[b * 512 + tid]       = e0 * inv;
  attn2[b * 512 + 256 + tid] = e1 * inv;
}

// ---------------------------------------------------------------------------
// Fw = a0*FR + a1*FN
// ---------------------------------------------------------------------------
__global__ __launch_bounds__(256)
void fw_kernel(const float* __restrict__ FR, const float* __restrict__ FN,
               const float* __restrict__ attn2, float* __restrict__ FW)
{
  const int b = blockIdx.z, c = blockIdx.y;
  const float a0 = attn2[b * 512 + c];
  const float a1 = attn2[b * 512 + 256 + c];
  const long base4 = ((long)b * 256 + c) * 1024;
  const int i = blockIdx.x * 256 + threadIdx.x;
  const float4 r = ((const float4*)FR)[base4 + i];
  const float4 n = ((const float4*)FN)[base4 + i];
  float4 o;
  o.x = a0 * r.x + a1 * n.x;
  o.y = a0 * r.y + a1 * n.y;
  o.z = a0 * r.z + a1 * n.z;
  o.w = a0 * r.w + a1 * n.w;
  ((float4*)FW)[base4 + i] = o;
}

// ---------------------------------------------------------------------------
// Depthwise 3x3, SAME padding; optional index-reversed copy for logits GEMM.
// ---------------------------------------------------------------------------
__global__ __launch_bounds__(256)
void dw_kernel(const float* __restrict__ in, const float* __restrict__ w,
               const float* __restrict__ bias, float* __restrict__ out,
               float* __restrict__ out_rev)
{
  __shared__ float img[66][66];
  const int bc = blockIdx.x, tid = threadIdx.x;
  const int c = bc & 255;
  for (int v = tid; v < 66 * 66; v += 256) ((float*)img)[v] = 0.f;
  __syncthreads();
  const float4* in4 = (const float4*)(in + (long)bc * HW);
  for (int v = tid; v < 1024; v += 256) {
    const float4 x = in4[v];
    const int r = v >> 4, c0 = ((v & 15) << 2) + 1;
    img[r + 1][c0 + 0] = x.x;
    img[r + 1][c0 + 1] = x.y;
    img[r + 1][c0 + 2] = x.z;
    img[r + 1][c0 + 3] = x.w;
  }
  float wr[9];
#pragma unroll
  for (int j = 0; j < 9; ++j) wr[j] = w[c * 9 + j];
  const float bb = bias[c];
  __syncthreads();
  for (int p = tid; p < 4096; p += 256) {
    const int y = p >> 6, x = p & 63;
    float s = bb;
#pragma unroll
    for (int ky = 0; ky < 3; ++ky)
#pragma unroll
      for (int kx = 0; kx < 3; ++kx)
        s = fmaf(wr[ky * 3 + kx], img[y + ky][x + kx], s);
    out[(long)bc * HW + p] = s;
    if (out_rev)
      out_rev[(long)bc * HW + (((64 - y) & 63) << 6) + ((64 - x) & 63)] = s;
  }
}

// ---------------------------------------------------------------------------
// S[b,c] = circconv2(Q[b,c], K[b,c]), real, via ONE packed FFT:
//   Z = fft2(Q + iK)   (radix-4 DIT, digit-reversed scatter load, natural out)
//   P(u,v) = FQ*FK = -i/4 * (Z(u,v)^2 - conj(Z(-u,-v))^2)
//   S = ifft2(P)       (radix-4 DIF, natural in, digit-reversed out -> store)
// SoA Re/Im with XOR swizzle; lane=line, wave=butterfly => <=2-way banks.
// LDS: 32KB data + 512B twiddles -> 4 blocks/CU.
// ---------------------------------------------------------------------------
#define SWA(r, c) (((r) << 6) | ((c) ^ (r)))
#define REV6(x)   ((((x) & 3) << 4) | ((x) & 12) | ((x) >> 4))

__device__ __forceinline__ float2 cmul(float2 a, float2 w) {
  return make_float2(a.x * w.x - a.y * w.y, a.x * w.y + a.y * w.x);
}
__device__ __forceinline__ float2 cmulc(float2 a, float2 w) {  // a * conj(w)
  return make_float2(a.x * w.x + a.y * w.y, a.y * w.x - a.x * w.y);
}

__global__ __launch_bounds__(256, 4)
void sconv_kernel(const float* __restrict__ Qg, const float* __restrict__ Kg,
                  float* __restrict__ Sg)
{
  __shared__ float Re[4096];
  __shared__ float Im[4096];
  __shared__ float2 twt[64];
  const int tid = threadIdx.x;
  const long base = (long)blockIdx.x * 4096;
  if (tid < 64) {
    float sn, cs;
    __sincosf(-2.f * (float)M_PI * (float)tid * (1.f / 64.f), &sn, &cs);
    twt[tid] = make_float2(cs, sn);   // W^tid = exp(-2*pi*i*tid/64)
  }
  const float4* Q4 = (const float4*)(Qg + base);
  const float4* K4 = (const float4*)(Kg + base);
#pragma unroll
  for (int i = 0; i < 4; ++i) {
    const int v = tid + 256 * i;
    const float4 q = Q4[v], k = K4[v];
    const int r = v >> 4, w = v & 15;
    const int R  = REV6(r);
    const int cb = ((w & 3) << 2) | (w >> 2);   // rev(4*w)
    Re[SWA(R, cb)]      = q.x;  Im[SWA(R, cb)]      = k.x;
    Re[SWA(R, cb + 16)] = q.y;  Im[SWA(R, cb + 16)] = k.y;
    Re[SWA(R, cb + 32)] = q.z;  Im[SWA(R, cb + 32)] = k.z;
    Re[SWA(R, cb + 48)] = q.w;  Im[SWA(R, cb + 48)] = k.w;
  }
  __syncthreads();

  const int lane = tid & 63;
  const int kb   = tid >> 6;

  // ---- forward radix-4 DIT: pass 0 = rows, pass 1 = cols ----
  for (int pass = 0; pass < 2; ++pass) {
    for (int s = 0; s < 3; ++s) {
      const int h  = 1 << (2 * s);
      const int us = 16 >> (2 * s);
#pragma unroll
      for (int q = 0; q < 4; ++q) {
        const int k = kb + 4 * q;
        const int j = k & (h - 1);
        const int g = k >> (2 * s);
        const int bse = g * 4 * h + j;
        const int p0 = bse, p1 = bse + h, p2 = bse + 2 * h, p3 = bse + 3 * h;
        const int a0 = pass ? SWA(p0, lane) : SWA(lane, p0);
        const int a1 = pass ? SWA(p1, lane) : SWA(lane, p1);
        const int a2 = pass ? SWA(p2, lane) : SWA(lane, p2);
        const int a3 = pass ? SWA(p3, lane) : SWA(lane, p3);
        float2 x0 = make_float2(Re[a0], Im[a0]);
        float2 x1 = make_float2(Re[a1], Im[a1]);
        float2 x2 = make_float2(Re[a2], Im[a2]);
        float2 x3 = make_float2(Re[a3], Im[a3]);
        const int e = j * us;
        x1 = cmul(x1, twt[e & 63]);
        x2 = cmul(x2, twt[(2 * e) & 63]);
        x3 = cmul(x3, twt[(3 * e) & 63]);
        const float2 t0 = make_float2(x0.x + x2.x, x0.y + x2.y);
        const float2 t1 = make_float2(x0.x - x2.x, x0.y - x2.y);
        const float2 t2 = make_float2(x1.x + x3.x, x1.y + x3.y);
        const float2 t3 = make_float2(x1.x - x3.x, x1.y - x3.y);
        Re[a0] = t0.x + t2.x;  Im[a0] = t0.y + t2.y;
        Re[a2] = t0.x - t2.x;  Im[a2] = t0.y - t2.y;
        Re[a1] = t1.x + t3.y;  Im[a1] = t1.y - t3.x;   // t1 - i*t3
        Re[a3] = t1.x - t3.y;  Im[a3] = t1.y + t3.x;   // t1 + i*t3
      }
      __syncthreads();
    }
  }

  // ---- pointwise: P = -i/4 * (Z^2 - conj(Z(-u,-v))^2) ----
  float2 pv[16];
#pragma unroll
  for (int i = 0; i < 16; ++i) {
    const int n = tid + 256 * i;
    const int u = n >> 6, vv = n & 63;
    const int u2 = (64 - u) & 63, v2 = (64 - vv) & 63;
    const int az = SWA(u, vv), am = SWA(u2, v2);
    const float zr = Re[az], zi = Im[az];
    const float mr = Re[am], mi = Im[am];
    const float dre = zr * zr - zi * zi - mr * mr + mi * mi;
    const float dim = 2.f * (zr * zi + mr * mi);
    pv[i] = make_float2(0.25f * dim, -0.25f * dre);
  }
  __syncthreads();
#pragma unroll
  for (int i = 0; i < 16; ++i) {
    const int n = tid + 256 * i;
    const int az = SWA(n >> 6, n & 63);
    Re[az] = pv[i].x;
    Im[az] = pv[i].y;
  }
  __syncthreads();

  // ---- inverse radix-4 DIF: pass 0 = cols, pass 1 = rows ----
  for (int pass = 0; pass < 2; ++pass) {
    for (int s = 2; s >= 0; --s) {
      const int h  = 1 << (2 * s);
      const int us = 16 >> (2 * s);
#pragma unroll
      for (int q = 0; q < 4; ++q) {
        const int k = kb + 4 * q;
        const int j = k & (h - 1);
        const int g = k >> (2 * s);
        const int bse = g * 4 * h + j;
        const int p0 = bse, p1 = bse + h, p2 = bse + 2 * h, p3 = bse + 3 * h;
        const int a0 = pass ? SWA(lane, p0) : SWA(p0, lane);
        const int a1 = pass ? SWA(lane, p1) : SWA(p1, lane);
        const int a2 = pass ? SWA(lane, p2) : SWA(p2, lane);
        const int a3 = pass ? SWA(lane, p3) : SWA(p3, lane);
        const float2 x0 = make_float2(Re[a0], Im[a0]);
        const float2 x1 = make_float2(Re[a1], Im[a1]);
        const float2 x2 = make_float2(Re[a2], Im[a2]);
        const float2 x3 = make_float2(Re[a3], Im[a3]);
        const float2 t0 = make_float2(x0.x + x2.x, x0.y + x2.y);
        const float2 t1 = make_float2(x0.x - x2.x, x0.y - x2.y);
        const float2 t2 = make_float2(x1.x + x3.x, x1.y + x3.y);
        const float2 t3 = make_float2(x1.x - x3.x, x1.y - x3.y);
        const float2 y0 = make_float2(t0.x + t2.x, t0.y + t2.y);
        float2 y2 = make_float2(t0.x - t2.x, t0.y - t2.y);
        float2 y1 = make_float2(t1.x - t3.y, t1.y + t3.x);   // t1 + i*t3
        float2 y3 = make_float2(t1.x + t3.y, t1.y - t3.x);   // t1 - i*t3
        const int e = j * us;
        y1 = cmulc(y1, twt[e & 63]);
        y2 = cmulc(y2, twt[(2 * e) & 63]);
        y3 = cmulc(y3, twt[(3 * e) & 63]);
        Re[a0] = y0.x;  Im[a0] = y0.y;
        Re[a1] = y1.x;  Im[a1] = y1.y;
        Re[a2] = y2.x;  Im[a2] = y2.y;
        Re[a3] = y3.x;  Im[a3] = y3.y;
      }
      __syncthreads();
    }
  }

  // ---- store: natural (y,x) lives at LDS (rev(y), rev(x)); scale 1/4096 ----
  float4* S4 = (float4*)(Sg + base);
#pragma unroll
  for (int i = 0; i < 4; ++i) {
    const int v = tid + 256 * i;
    const int y = v >> 4, w = v & 15;
    const int Rr = REV6(y);
    const int cb = ((w & 3) << 2) | (w >> 2);
    float4 o;
    o.x = Re[SWA(Rr, cb)]      * (1.f / 4096.f);
    o.y = Re[SWA(Rr, cb + 16)] * (1.f / 4096.f);
    o.z = Re[SWA(Rr, cb + 32)] * (1.f / 4096.f);
    o.w = Re[SWA(Rr, cb + 48)] * (1.f / 4096.f);
    S4[v] = o;
  }
}

// ---------------------------------------------------------------------------
// row-wise softmax over d of |L| * 4096/alpha
// ---------------------------------------------------------------------------
__global__ __launch_bounds__(256)
void softmax_kernel(float* __restrict__ L, const float* __restrict__ alpha)
{
  __shared__ float red[256];
  const int row = blockIdx.x, tid = threadIdx.x;
  const float sc = 4096.f / alpha[0];
  float* p = L + (long)row * 256;
  const float v = fabsf(p[tid]) * sc;
  red[tid] = v; __syncthreads();
  for (int o = 128; o > 0; o >>= 1) {
    if (tid < o) red[tid] = fmaxf(red[tid], red[tid + o]);
    __syncthreads();
  }
  const float mx = red[0];
  __syncthreads();
  const float e = expf(v - mx);
  red[tid] = e; __syncthreads();
  for (int o = 128; o > 0; o >>= 1) {
    if (tid < o) red[tid] += red[tid + o];
    __syncthreads();
  }
  p[tid] = e / red[0];
}

// ---------------------------------------------------------------------------
extern "C" void kernel_launch(void* const* d_in, const int* in_sizes, int n_in,
                              void* d_out, int out_size, void* d_ws, size_t ws_size,
                              hipStream_t stream)
{
  const float* x1       = (const float*)d_in[0];
  const float* x2       = (const float*)d_in[1];
  const float* conv_r_w = (const float*)d_in[2];
  const float* conv_r_b = (const float*)d_in[3];
  const float* conv_n_w = (const float*)d_in[4];
  const float* conv_n_b = (const float*)d_in[5];
  const float* mlp_w1   = (const float*)d_in[6];
  const float* mlp_w2   = (const float*)d_in[7];
  const float* pq_w     = (const float*)d_in[8];
  const float* pq_b     = (const float*)d_in[9];
  const float* dq_w     = (const float*)d_in[10];
  const float* dq_b     = (const float*)d_in[11];
  const float* pk_w     = (const float*)d_in[12];
  const float* pk_b     = (const float*)d_in[13];
  const float* dk_w     = (const float*)d_in[14];
  const float* dk_b     = (const float*)d_in[15];
  const float* pv_w     = (const float*)d_in[16];
  const float* pv_b     = (const float*)d_in[17];
  const float* dv_w     = (const float*)d_in[18];
  const float* dv_b     = (const float*)d_in[19];
  const float* out_w    = (const float*)d_in[20];
  const float* out_b    = (const float*)d_in[21];
  const float* alpha    = (const float*)d_in[22];
  const float* lambd    = (const float*)d_in[23];
  const float* beta     = (const float*)d_in[24];

  float* s = (float*)d_ws;
  float* S0 = s;             // FR  -> Q
  float* S1 = s + SLOT;      // FN  -> K
  float* S2 = s + 2 * SLOT;  // Fw  -> mix (in-place)
  float* S3 = s + 3 * SLOT;  // Pq  -> Krev
  float* S4 = s + 4 * SLOT;  // Pk  -> V
  float* S5 = s + 5 * SLOT;  // Pv  -> S
  float* Lb     = s + 6 * SLOT;          // [8,256,256]
  float* pooled = Lb + (long)8 * 256 * 256;
  float* attn2  = pooled + 2048;

  const size_t needed = (size_t)(6 * SLOT + 8L * 256 * 256 + 2048 + 4096) * sizeof(float);
  if (ws_size < needed) return;

  const long ST  = (long)CH * HW;   // 1048576
  const long ST2 = (long)128 * HW;
  const long STL = (long)256 * 256;

  hipMemsetAsync(Lb, 0, (size_t)8 * 256 * 256 * sizeof(float), stream);

  // FR = conv_r(x1), FN = conv_n(x2)
  gemm_kernel<false, 0><<<dim3(32, 2, 8), 256, 0, stream>>>(
      conv_r_w, x1, S0, conv_r_b, 256, 4096, 256, 1, 0L, ST, ST,
      nullptr, nullptr, nullptr, nullptr, nullptr);
  gemm_kernel<false, 0><<<dim3(32, 2, 8), 256, 0, stream>>>(
      conv_n_w, x2, S1, conv_n_b, 256, 4096, 128, 1, 0L, ST2, ST,
      nullptr, nullptr, nullptr, nullptr, nullptr);

  pool_kernel<<<2048, 256, 0, stream>>>(S0, S1, pooled);
  attn2_kernel<<<8, 256, 0, stream>>>(pooled, mlp_w1, mlp_w2, attn2);
  fw_kernel<<<dim3(4, 256, 8), 256, 0, stream>>>(S0, S1, attn2, S2);

  // Pq/Pk/Pv = 1x1 convs of Fw
  gemm_kernel<false, 0><<<dim3(32, 2, 8), 256, 0, stream>>>(
      pq_w, S2, S3, pq_b, 256, 4096, 256, 1, 0L, ST, ST,
      nullptr, nullptr, nullptr, nullptr, nullptr);
  gemm_kernel<false, 0><<<dim3(32, 2, 8), 256, 0, stream>>>(
      pk_w, S2, S4, pk_b, 256, 4096, 256, 1, 0L, ST, ST,
      nullptr, nullptr, nullptr, nullptr, nullptr);
  gemm_kernel<false, 0><<<dim3(32, 2, 8), 256, 0, stream>>>(
      pv_w, S2, S5, pv_b, 256, 4096, 256, 1, 0L, ST, ST,
      nullptr, nullptr, nullptr, nullptr, nullptr);

  // depthwise 3x3
  dw_kernel<<<2048, 256, 0, stream>>>(S3, dq_w, dq_b, S0, nullptr);  // Q  -> S0
  dw_kernel<<<2048, 256, 0, stream>>>(S4, dk_w, dk_b, S1, S3);       // K  -> S1, Krev -> S3
  dw_kernel<<<2048, 256, 0, stream>>>(S5, dv_w, dv_b, S4, nullptr);  // V  -> S4

  // S = circconv2(Q, K) per channel (packed single-FFT version)
  sconv_kernel<<<2048, 256, 0, stream>>>(S0, S1, S5);                // S -> S5

  // attn logits: L = Q . Krev  (split-K=16, fp32 atomic accumulate)
  gemm_kernel<true, 1><<<dim3(2, 2, 128), 256, 0, stream>>>(
      S0, S3, Lb, nullptr, 256, 256, 4096, 16, ST, ST, STL,
      nullptr, nullptr, nullptr, nullptr, nullptr);

  softmax_kernel<<<2048, 256, 0, stream>>>(Lb, alpha);

  // cfr = attn_w @ S, fused mix epilogue (in-place into S2)
  gemm_kernel<false, 2><<<dim3(32, 2, 8), 256, 0, stream>>>(
      Lb, S5, S2, nullptr, 256, 4096, 256, 1, STL, ST, ST,
      S0, S4, S2, lambd, beta);

  // final 1x1 conv -> d_out
  gemm_kernel<false, 0><<<dim3(32, 2, 8), 256, 0, stream>>>(
      out_w, S2, (float*)d_out, out_b, 256, 4096, 256, 1, 0L, ST, ST,
      nullptr, nullptr, nullptr, nullptr, nullptr);
}

// Round 3
// 998.692 us; speedup vs baseline: 1.0643x; 1.0643x over previous
//
#include <hip/hip_runtime.h>
#include <math.h>

#ifndef M_PI
#define M_PI 3.14159265358979323846
#endif

// Problem constants
constexpr int  NB   = 8;
constexpr int  CH   = 256;
constexpr long HW   = 4096;                 // 64*64
constexpr long SLOT = (long)NB * CH * HW;   // floats per [8,256,64,64] tensor

// ---------------------------------------------------------------------------
// Tiled SGEMM:  C[b] (MxN) = A[b] (MxK) * B[b] (KxN)   (or B is [N,K] if BT)
// Tile 128(M) x 128(N), BK=16, 256 threads, 8x8 microtile per thread.
// Register-prefetch pipeline: next global tile loads issue right after the
// barrier, overlapping the 16-step FMA loop.
// NOTE: no second __launch_bounds__ arg — round 2 showed it caps VGPRs at ~68
// and spills acc[8][8] to scratch (WRITE_SIZE 33->256 MB, VALUBusy 7.5%).
// EPI 0: bias (nullable) + store.  EPI 1: atomicAdd (split-K accumulate).
// EPI 2: cfr->mix fused epilogue: mix = beta*(cfr*(Q - lam*V) + V) + (1-beta)*Fw
// ---------------------------------------------------------------------------
template<bool BT, int EPI>
__global__ __launch_bounds__(256)
void gemm_kernel(const float* __restrict__ A, const float* __restrict__ B,
                 float* __restrict__ C, const float* __restrict__ bias,
                 int M, int N, int K, int nSplitK,
                 long aStride, long bStride, long cStride,
                 const float* __restrict__ qb, const float* __restrict__ vb,
                 const float* __restrict__ fwb,
                 const float* __restrict__ lambd, const float* __restrict__ beta)
{
  __shared__ __align__(16) float As[16][132];   // [k][m]
  __shared__ __align__(16) float Bs[16][132];   // [k][n]
  const int tid = threadIdx.x;
  const int b   = blockIdx.z / nSplitK;
  const int ks  = blockIdx.z % nSplitK;
  const int kLen = K / nSplitK;
  const int k0b  = ks * kLen;
  const float* Ab = A + (long)b * aStride;
  const float* Bb = B + (long)b * bStride;
  float* Cb = C + (long)b * cStride;
  const int m0 = blockIdx.y * 128;
  const int n0 = blockIdx.x * 128;

  float acc[8][8];
#pragma unroll
  for (int i = 0; i < 8; ++i)
#pragma unroll
    for (int j = 0; j < 8; ++j) acc[i][j] = 0.f;

  const int tx = tid & 15;        // n octet
  const int ty = tid >> 4;        // m octet
  const int lr = tid >> 1;        // 0..127: A row (or B row for BT)
  const int lk = (tid & 1) * 8;   // k offset 0/8
  const int bn = (tid & 31) * 4;  // B col (!BT)
  const int bk = tid >> 5;        // 0..7   (!BT)

  // prefetch tile 0 into registers
  float4 pa0, pa1, pb0, pb1;
  {
    const float* ap = &Ab[(long)(m0 + lr) * K + k0b + lk];
    pa0 = *(const float4*)ap;
    pa1 = *(const float4*)(ap + 4);
    if (BT) {
      const float* bp = &Bb[(long)(n0 + lr) * K + k0b + lk];
      pb0 = *(const float4*)bp;
      pb1 = *(const float4*)(bp + 4);
    } else {
      pb0 = *(const float4*)&Bb[(long)(k0b + bk) * N + n0 + bn];
      pb1 = *(const float4*)&Bb[(long)(k0b + bk + 8) * N + n0 + bn];
    }
  }

  for (int kt = 0; kt < kLen; kt += 16) {
    // commit staged registers to LDS
    As[lk+0][lr] = pa0.x; As[lk+1][lr] = pa0.y; As[lk+2][lr] = pa0.z; As[lk+3][lr] = pa0.w;
    As[lk+4][lr] = pa1.x; As[lk+5][lr] = pa1.y; As[lk+6][lr] = pa1.z; As[lk+7][lr] = pa1.w;
    if (BT) {
      Bs[lk+0][lr] = pb0.x; Bs[lk+1][lr] = pb0.y; Bs[lk+2][lr] = pb0.z; Bs[lk+3][lr] = pb0.w;
      Bs[lk+4][lr] = pb1.x; Bs[lk+5][lr] = pb1.y; Bs[lk+6][lr] = pb1.z; Bs[lk+7][lr] = pb1.w;
    } else {
      *(float4*)&Bs[bk][bn]     = pb0;
      *(float4*)&Bs[bk + 8][bn] = pb1;
    }
    __syncthreads();

    // issue next tile's global loads (overlap with FMA loop below)
    if (kt + 16 < kLen) {
      const int k0 = k0b + kt + 16;
      const float* ap = &Ab[(long)(m0 + lr) * K + k0 + lk];
      pa0 = *(const float4*)ap;
      pa1 = *(const float4*)(ap + 4);
      if (BT) {
        const float* bp = &Bb[(long)(n0 + lr) * K + k0 + lk];
        pb0 = *(const float4*)bp;
        pb1 = *(const float4*)(bp + 4);
      } else {
        pb0 = *(const float4*)&Bb[(long)(k0 + bk) * N + n0 + bn];
        pb1 = *(const float4*)&Bb[(long)(k0 + bk + 8) * N + n0 + bn];
      }
    }

#pragma unroll
    for (int kk = 0; kk < 16; ++kk) {
      const float4 a0 = *(const float4*)&As[kk][ty * 8];
      const float4 a1 = *(const float4*)&As[kk][ty * 8 + 4];
      const float4 b0 = *(const float4*)&Bs[kk][tx * 8];
      const float4 b1 = *(const float4*)&Bs[kk][tx * 8 + 4];
      const float av[8] = {a0.x, a0.y, a0.z, a0.w, a1.x, a1.y, a1.z, a1.w};
      const float bv[8] = {b0.x, b0.y, b0.z, b0.w, b1.x, b1.y, b1.z, b1.w};
#pragma unroll
      for (int i = 0; i < 8; ++i)
#pragma unroll
        for (int j = 0; j < 8; ++j)
          acc[i][j] = fmaf(av[i], bv[j], acc[i][j]);
    }
    __syncthreads();
  }

  if (EPI == 0) {
#pragma unroll
    for (int i = 0; i < 8; ++i) {
      const int row = m0 + ty * 8 + i;
      const float bb = bias ? bias[row] : 0.f;
      float4 r0, r1;
      r0.x = acc[i][0] + bb; r0.y = acc[i][1] + bb; r0.z = acc[i][2] + bb; r0.w = acc[i][3] + bb;
      r1.x = acc[i][4] + bb; r1.y = acc[i][5] + bb; r1.z = acc[i][6] + bb; r1.w = acc[i][7] + bb;
      float* p = &Cb[(long)row * N + n0 + tx * 8];
      *(float4*)p       = r0;
      *(float4*)(p + 4) = r1;
    }
  } else if (EPI == 1) {
#pragma unroll
    for (int i = 0; i < 8; ++i) {
      const int row = m0 + ty * 8 + i;
      float* p = &Cb[(long)row * N + n0 + tx * 8];
#pragma unroll
      for (int j = 0; j < 8; ++j) atomicAdd(p + j, acc[i][j]);
    }
  } else {
    const float lam = lambd[0], bet = beta[0];
#pragma unroll
    for (int i = 0; i < 8; ++i) {
      const int row = m0 + ty * 8 + i;
      const long off = (long)row * N + n0 + tx * 8;
      const long gi  = (long)b * cStride + off;
      const float4 q0 = *(const float4*)&qb[gi],  q1 = *(const float4*)&qb[gi + 4];
      const float4 v0 = *(const float4*)&vb[gi],  v1 = *(const float4*)&vb[gi + 4];
      const float4 f0 = *(const float4*)&fwb[gi], f1 = *(const float4*)&fwb[gi + 4];
      const float qv[8] = {q0.x,q0.y,q0.z,q0.w,q1.x,q1.y,q1.z,q1.w};
      const float vv[8] = {v0.x,v0.y,v0.z,v0.w,v1.x,v1.y,v1.z,v1.w};
      const float fv[8] = {f0.x,f0.y,f0.z,f0.w,f1.x,f1.y,f1.z,f1.w};
      float r[8];
#pragma unroll
      for (int j = 0; j < 8; ++j)
        r[j] = bet * (acc[i][j] * (qv[j] - lam * vv[j]) + vv[j]) + (1.f - bet) * fv[j];
      float* p = &Cb[off];
      *(float4*)p       = make_float4(r[0], r[1], r[2], r[3]);
      *(float4*)(p + 4) = make_float4(r[4], r[5], r[6], r[7]);
    }
  }
}

// ---------------------------------------------------------------------------
// pooled[b,c] = mean over HW of (FR + FN)
// ---------------------------------------------------------------------------
__global__ __launch_bounds__(256)
void pool_kernel(const float* __restrict__ FR, const float* __restrict__ FN,
                 float* __restrict__ pooled)
{
  __shared__ float red[256];
  const int bc = blockIdx.x, tid = threadIdx.x;
  const float4* a = (const float4*)(FR + (long)bc * HW);
  const float4* b = (const float4*)(FN + (long)bc * HW);
  float s = 0.f;
  for (int v = tid; v < 1024; v += 256) {
    const float4 x = a[v]; s += x.x + x.y + x.z + x.w;
    const float4 y = b[v]; s += y.x + y.y + y.z + y.w;
  }
  red[tid] = s; __syncthreads();
  for (int o = 128; o > 0; o >>= 1) {
    if (tid < o) red[tid] += red[tid + o];
    __syncthreads();
  }
  if (tid == 0) pooled[bc] = red[0] * (1.f / 4096.f);
}

// ---------------------------------------------------------------------------
// MLP (relu) + 2-way softmax -> attn2 [8,2,256]
// ---------------------------------------------------------------------------
__global__ __launch_bounds__(256)
void attn2_kernel(const float* __restrict__ pooled, const float* __restrict__ w1,
                  const float* __restrict__ w2, float* __restrict__ attn2)
{
  __shared__ float ps[256];
  __shared__ float hs[32];
  const int b = blockIdx.x, tid = threadIdx.x;
  ps[tid] = pooled[b * 256 + tid];
  __syncthreads();
  if (tid < 32) {
    float a = 0.f;
    for (int c = 0; c < 256; ++c) a += ps[c] * w1[tid * 256 + c];
    hs[tid] = fmaxf(a, 0.f);
  }
  __syncthreads();
  float a0 = 0.f, a1 = 0.f;
  for (int d = 0; d < 32; ++d) {
    const float h = hs[d];
    a0 += h * w2[tid * 32 + d];
    a1 += h * w2[(256 + tid) * 32 + d];
  }
  const float m  = fmaxf(a0, a1);
  const float e0 = expf(a0 - m), e1 = expf(a1 - m);
  const float inv = 1.f / (e0 + e1);
  attn2[b * 512 + tid]       = e0 * inv;
  attn2[b * 512 + 256 + tid] = e1 * inv;
}

// ---------------------------------------------------------------------------
// Fw = a0*FR + a1*FN
// ---------------------------------------------------------------------------
__global__ __launch_bounds__(256)
void fw_kernel(const float* __restrict__ FR, const float* __restrict__ FN,
               const float* __restrict__ attn2, float* __restrict__ FW)
{
  const int b = blockIdx.z, c = blockIdx.y;
  const float a0 = attn2[b * 512 + c];
  const float a1 = attn2[b * 512 + 256 + c];
  const long base4 = ((long)b * 256 + c) * 1024;
  const int i = blockIdx.x * 256 + threadIdx.x;
  const float4 r = ((const float4*)FR)[base4 + i];
  const float4 n = ((const float4*)FN)[base4 + i];
  float4 o;
  o.x = a0 * r.x + a1 * n.x;
  o.y = a0 * r.y + a1 * n.y;
  o.z = a0 * r.z + a1 * n.z;
  o.w = a0 * r.w + a1 * n.w;
  ((float4*)FW)[base4 + i] = o;
}

// ---------------------------------------------------------------------------
// Depthwise 3x3, SAME padding; optional index-reversed copy for logits GEMM.
// ---------------------------------------------------------------------------
__global__ __launch_bounds__(256)
void dw_kernel(const float* __restrict__ in, const float* __restrict__ w,
               const float* __restrict__ bias, float* __restrict__ out,
               float* __restrict__ out_rev)
{
  __shared__ float img[66][66];
  const int bc = blockIdx.x, tid = threadIdx.x;
  const int c = bc & 255;
  for (int v = tid; v < 66 * 66; v += 256) ((float*)img)[v] = 0.f;
  __syncthreads();
  const float4* in4 = (const float4*)(in + (long)bc * HW);
  for (int v = tid; v < 1024; v += 256) {
    const float4 x = in4[v];
    const int r = v >> 4, c0 = ((v & 15) << 2) + 1;
    img[r + 1][c0 + 0] = x.x;
    img[r + 1][c0 + 1] = x.y;
    img[r + 1][c0 + 2] = x.z;
    img[r + 1][c0 + 3] = x.w;
  }
  float wr[9];
#pragma unroll
  for (int j = 0; j < 9; ++j) wr[j] = w[c * 9 + j];
  const float bb = bias[c];
  __syncthreads();
  for (int p = tid; p < 4096; p += 256) {
    const int y = p >> 6, x = p & 63;
    float s = bb;
#pragma unroll
    for (int ky = 0; ky < 3; ++ky)
#pragma unroll
      for (int kx = 0; kx < 3; ++kx)
        s = fmaf(wr[ky * 3 + kx], img[y + ky][x + kx], s);
    out[(long)bc * HW + p] = s;
    if (out_rev)
      out_rev[(long)bc * HW + (((64 - y) & 63) << 6) + ((64 - x) & 63)] = s;
  }
}

// ---------------------------------------------------------------------------
// S[b,c] = circconv2(Q[b,c], K[b,c]), real, via ONE packed FFT:
//   Z = fft2(Q + iK)   (radix-4 DIT, digit-reversed scatter load, natural out)
//   P(u,v) = FQ*FK = -i/4 * (Z(u,v)^2 - conj(Z(-u,-v))^2)
//   S = ifft2(P)       (radix-4 DIF, natural in, digit-reversed out -> store)
// SoA Re/Im with XOR swizzle; lane=line, wave=butterfly => <=2-way banks.
// ---------------------------------------------------------------------------
#define SWA(r, c) (((r) << 6) | ((c) ^ (r)))
#define REV6(x)   ((((x) & 3) << 4) | ((x) & 12) | ((x) >> 4))

__device__ __forceinline__ float2 cmul(float2 a, float2 w) {
  return make_float2(a.x * w.x - a.y * w.y, a.x * w.y + a.y * w.x);
}
__device__ __forceinline__ float2 cmulc(float2 a, float2 w) {  // a * conj(w)
  return make_float2(a.x * w.x + a.y * w.y, a.y * w.x - a.x * w.y);
}

__global__ __launch_bounds__(256, 4)
void sconv_kernel(const float* __restrict__ Qg, const float* __restrict__ Kg,
                  float* __restrict__ Sg)
{
  __shared__ float Re[4096];
  __shared__ float Im[4096];
  __shared__ float2 twt[64];
  const int tid = threadIdx.x;
  const long base = (long)blockIdx.x * 4096;
  if (tid < 64) {
    float sn, cs;
    __sincosf(-2.f * (float)M_PI * (float)tid * (1.f / 64.f), &sn, &cs);
    twt[tid] = make_float2(cs, sn);   // W^tid = exp(-2*pi*i*tid/64)
  }
  const float4* Q4 = (const float4*)(Qg + base);
  const float4* K4 = (const float4*)(Kg + base);
#pragma unroll
  for (int i = 0; i < 4; ++i) {
    const int v = tid + 256 * i;
    const float4 q = Q4[v], k = K4[v];
    const int r = v >> 4, w = v & 15;
    const int R  = REV6(r);
    const int cb = ((w & 3) << 2) | (w >> 2);   // rev(4*w)
    Re[SWA(R, cb)]      = q.x;  Im[SWA(R, cb)]      = k.x;
    Re[SWA(R, cb + 16)] = q.y;  Im[SWA(R, cb + 16)] = k.y;
    Re[SWA(R, cb + 32)] = q.z;  Im[SWA(R, cb + 32)] = k.z;
    Re[SWA(R, cb + 48)] = q.w;  Im[SWA(R, cb + 48)] = k.w;
  }
  __syncthreads();

  const int lane = tid & 63;
  const int kb   = tid >> 6;

  // ---- forward radix-4 DIT: pass 0 = rows, pass 1 = cols ----
  for (int pass = 0; pass < 2; ++pass) {
    for (int s = 0; s < 3; ++s) {
      const int h  = 1 << (2 * s);
      const int us = 16 >> (2 * s);
#pragma unroll
      for (int q = 0; q < 4; ++q) {
        const int k = kb + 4 * q;
        const int j = k & (h - 1);
        const int g = k >> (2 * s);
        const int bse = g * 4 * h + j;
        const int p0 = bse, p1 = bse + h, p2 = bse + 2 * h, p3 = bse + 3 * h;
        const int a0 = pass ? SWA(p0, lane) : SWA(lane, p0);
        const int a1 = pass ? SWA(p1, lane) : SWA(lane, p1);
        const int a2 = pass ? SWA(p2, lane) : SWA(lane, p2);
        const int a3 = pass ? SWA(p3, lane) : SWA(lane, p3);
        float2 x0 = make_float2(Re[a0], Im[a0]);
        float2 x1 = make_float2(Re[a1], Im[a1]);
        float2 x2 = make_float2(Re[a2], Im[a2]);
        float2 x3 = make_float2(Re[a3], Im[a3]);
        const int e = j * us;
        x1 = cmul(x1, twt[e & 63]);
        x2 = cmul(x2, twt[(2 * e) & 63]);
        x3 = cmul(x3, twt[(3 * e) & 63]);
        const float2 t0 = make_float2(x0.x + x2.x, x0.y + x2.y);
        const float2 t1 = make_float2(x0.x - x2.x, x0.y - x2.y);
        const float2 t2 = make_float2(x1.x + x3.x, x1.y + x3.y);
        const float2 t3 = make_float2(x1.x - x3.x, x1.y - x3.y);
        Re[a0] = t0.x + t2.x;  Im[a0] = t0.y + t2.y;
        Re[a2] = t0.x - t2.x;  Im[a2] = t0.y - t2.y;
        Re[a1] = t1.x + t3.y;  Im[a1] = t1.y - t3.x;   // t1 - i*t3
        Re[a3] = t1.x - t3.y;  Im[a3] = t1.y + t3.x;   // t1 + i*t3
      }
      __syncthreads();
    }
  }

  // ---- pointwise: P = -i/4 * (Z^2 - conj(Z(-u,-v))^2) ----
  float2 pv[16];
#pragma unroll
  for (int i = 0; i < 16; ++i) {
    const int n = tid + 256 * i;
    const int u = n >> 6, vv = n & 63;
    const int u2 = (64 - u) & 63, v2 = (64 - vv) & 63;
    const int az = SWA(u, vv), am = SWA(u2, v2);
    const float zr = Re[az], zi = Im[az];
    const float mr = Re[am], mi = Im[am];
    const float dre = zr * zr - zi * zi - mr * mr + mi * mi;
    const float dim = 2.f * (zr * zi + mr * mi);
    pv[i] = make_float2(0.25f * dim, -0.25f * dre);
  }
  __syncthreads();
#pragma unroll
  for (int i = 0; i < 16; ++i) {
    const int n = tid + 256 * i;
    const int az = SWA(n >> 6, n & 63);
    Re[az] = pv[i].x;
    Im[az] = pv[i].y;
  }
  __syncthreads();

  // ---- inverse radix-4 DIF: pass 0 = cols, pass 1 = rows ----
  for (int pass = 0; pass < 2; ++pass) {
    for (int s = 2; s >= 0; --s) {
      const int h  = 1 << (2 * s);
      const int us = 16 >> (2 * s);
#pragma unroll
      for (int q = 0; q < 4; ++q) {
        const int k = kb + 4 * q;
        const int j = k & (h - 1);
        const int g = k >> (2 * s);
        const int bse = g * 4 * h + j;
        const int p0 = bse, p1 = bse + h, p2 = bse + 2 * h, p3 = bse + 3 * h;
        const int a0 = pass ? SWA(lane, p0) : SWA(p0, lane);
        const int a1 = pass ? SWA(lane, p1) : SWA(p1, lane);
        const int a2 = pass ? SWA(lane, p2) : SWA(p2, lane);
        const int a3 = pass ? SWA(lane, p3) : SWA(p3, lane);
        const float2 x0 = make_float2(Re[a0], Im[a0]);
        const float2 x1 = make_float2(Re[a1], Im[a1]);
        const float2 x2 = make_float2(Re[a2], Im[a2]);
        const float2 x3 = make_float2(Re[a3], Im[a3]);
        const float2 t0 = make_float2(x0.x + x2.x, x0.y + x2.y);
        const float2 t1 = make_float2(x0.x - x2.x, x0.y - x2.y);
        const float2 t2 = make_float2(x1.x + x3.x, x1.y + x3.y);
        const float2 t3 = make_float2(x1.x - x3.x, x1.y - x3.y);
        const float2 y0 = make_float2(t0.x + t2.x, t0.y + t2.y);
        float2 y2 = make_float2(t0.x - t2.x, t0.y - t2.y);
        float2 y1 = make_float2(t1.x - t3.y, t1.y + t3.x);   // t1 + i*t3
        float2 y3 = make_float2(t1.x + t3.y, t1.y - t3.x);   // t1 - i*t3
        const int e = j * us;
        y1 = cmulc(y1, twt[e & 63]);
        y2 = cmulc(y2, twt[(2 * e) & 63]);
        y3 = cmulc(y3, twt[(3 * e) & 63]);
        Re[a0] = y0.x;  Im[a0] = y0.y;
        Re[a1] = y1.x;  Im[a1] = y1.y;
        Re[a2] = y2.x;  Im[a2] = y2.y;
        Re[a3] = y3.x;  Im[a3] = y3.y;
      }
      __syncthreads();
    }
  }

  // ---- store: natural (y,x) lives at LDS (rev(y), rev(x)); scale 1/4096 ----
  float4* S4 = (float4*)(Sg + base);
#pragma unroll
  for (int i = 0; i < 4; ++i) {
    const int v = tid + 256 * i;
    const int y = v >> 4, w = v & 15;
    const int Rr = REV6(y);
    const int cb = ((w & 3) << 2) | (w >> 2);
    float4 o;
    o.x = Re[SWA(Rr, cb)]      * (1.f / 4096.f);
    o.y = Re[SWA(Rr, cb + 16)] * (1.f / 4096.f);
    o.z = Re[SWA(Rr, cb + 32)] * (1.f / 4096.f);
    o.w = Re[SWA(Rr, cb + 48)] * (1.f / 4096.f);
    S4[v] = o;
  }
}

// ---------------------------------------------------------------------------
// row-wise softmax over d of |L| * 4096/alpha
// ---------------------------------------------------------------------------
__global__ __launch_bounds__(256)
void softmax_kernel(float* __restrict__ L, const float* __restrict__ alpha)
{
  __shared__ float red[256];
  const int row = blockIdx.x, tid = threadIdx.x;
  const float sc = 4096.f / alpha[0];
  float* p = L + (long)row * 256;
  const float v = fabsf(p[tid]) * sc;
  red[tid] = v; __syncthreads();
  for (int o = 128; o > 0; o >>= 1) {
    if (tid < o) red[tid] = fmaxf(red[tid], red[tid + o]);
    __syncthreads();
  }
  const float mx = red[0];
  __syncthreads();
  const float e = expf(v - mx);
  red[tid] = e; __syncthreads();
  for (int o = 128; o > 0; o >>= 1) {
    if (tid < o) red[tid] += red[tid + o];
    __syncthreads();
  }
  p[tid] = e / red[0];
}

// ---------------------------------------------------------------------------
extern "C" void kernel_launch(void* const* d_in, const int* in_sizes, int n_in,
                              void* d_out, int out_size, void* d_ws, size_t ws_size,
                              hipStream_t stream)
{
  const float* x1       = (const float*)d_in[0];
  const float* x2       = (const float*)d_in[1];
  const float* conv_r_w = (const float*)d_in[2];
  const float* conv_r_b = (const float*)d_in[3];
  const float* conv_n_w = (const float*)d_in[4];
  const float* conv_n_b = (const float*)d_in[5];
  const float* mlp_w1   = (const float*)d_in[6];
  const float* mlp_w2   = (const float*)d_in[7];
  const float* pq_w     = (const float*)d_in[8];
  const float* pq_b     = (const float*)d_in[9];
  const float* dq_w     = (const float*)d_in[10];
  const float* dq_b     = (const float*)d_in[11];
  const float* pk_w     = (const float*)d_in[12];
  const float* pk_b     = (const float*)d_in[13];
  const float* dk_w     = (const float*)d_in[14];
  const float* dk_b     = (const float*)d_in[15];
  const float* pv_w     = (const float*)d_in[16];
  const float* pv_b     = (const float*)d_in[17];
  const float* dv_w     = (const float*)d_in[18];
  const float* dv_b     = (const float*)d_in[19];
  const float* out_w    = (const float*)d_in[20];
  const float* out_b    = (const float*)d_in[21];
  const float* alpha    = (const float*)d_in[22];
  const float* lambd    = (const float*)d_in[23];
  const float* beta     = (const float*)d_in[24];

  float* s = (float*)d_ws;
  float* S0 = s;             // FR  -> Q
  float* S1 = s + SLOT;      // FN  -> K
  float* S2 = s + 2 * SLOT;  // Fw  -> mix (in-place)
  float* S3 = s + 3 * SLOT;  // Pq  -> Krev
  float* S4 = s + 4 * SLOT;  // Pk  -> V
  float* S5 = s + 5 * SLOT;  // Pv  -> S
  float* Lb     = s + 6 * SLOT;          // [8,256,256]
  float* pooled = Lb + (long)8 * 256 * 256;
  float* attn2  = pooled + 2048;

  const size_t needed = (size_t)(6 * SLOT + 8L * 256 * 256 + 2048 + 4096) * sizeof(float);
  if (ws_size < needed) return;

  const long ST  = (long)CH * HW;   // 1048576
  const long ST2 = (long)128 * HW;
  const long STL = (long)256 * 256;

  hipMemsetAsync(Lb, 0, (size_t)8 * 256 * 256 * sizeof(float), stream);

  // FR = conv_r(x1), FN = conv_n(x2)
  gemm_kernel<false, 0><<<dim3(32, 2, 8), 256, 0, stream>>>(
      conv_r_w, x1, S0, conv_r_b, 256, 4096, 256, 1, 0L, ST, ST,
      nullptr, nullptr, nullptr, nullptr, nullptr);
  gemm_kernel<false, 0><<<dim3(32, 2, 8), 256, 0, stream>>>(
      conv_n_w, x2, S1, conv_n_b, 256, 4096, 128, 1, 0L, ST2, ST,
      nullptr, nullptr, nullptr, nullptr, nullptr);

  pool_kernel<<<2048, 256, 0, stream>>>(S0, S1, pooled);
  attn2_kernel<<<8, 256, 0, stream>>>(pooled, mlp_w1, mlp_w2, attn2);
  fw_kernel<<<dim3(4, 256, 8), 256, 0, stream>>>(S0, S1, attn2, S2);

  // Pq/Pk/Pv = 1x1 convs of Fw
  gemm_kernel<false, 0><<<dim3(32, 2, 8), 256, 0, stream>>>(
      pq_w, S2, S3, pq_b, 256, 4096, 256, 1, 0L, ST, ST,
      nullptr, nullptr, nullptr, nullptr, nullptr);
  gemm_kernel<false, 0><<<dim3(32, 2, 8), 256, 0, stream>>>(
      pk_w, S2, S4, pk_b, 256, 4096, 256, 1, 0L, ST, ST,
      nullptr, nullptr, nullptr, nullptr, nullptr);
  gemm_kernel<false, 0><<<dim3(32, 2, 8), 256, 0, stream>>>(
      pv_w, S2, S5, pv_b, 256, 4096, 256, 1, 0L, ST, ST,
      nullptr, nullptr, nullptr, nullptr, nullptr);

  // depthwise 3x3
  dw_kernel<<<2048, 256, 0, stream>>>(S3, dq_w, dq_b, S0, nullptr);  // Q  -> S0
  dw_kernel<<<2048, 256, 0, stream>>>(S4, dk_w, dk_b, S1, S3);       // K  -> S1, Krev -> S3
  dw_kernel<<<2048, 256, 0, stream>>>(S5, dv_w, dv_b, S4, nullptr);  // V  -> S4

  // S = circconv2(Q, K) per channel (packed single-FFT version)
  sconv_kernel<<<2048, 256, 0, stream>>>(S0, S1, S5);                // S -> S5

  // attn logits: L = Q . Krev  (split-K=16, fp32 atomic accumulate)
  gemm_kernel<true, 1><<<dim3(2, 2, 128), 256, 0, stream>>>(
      S0, S3, Lb, nullptr, 256, 256, 4096, 16, ST, ST, STL,
      nullptr, nullptr, nullptr, nullptr, nullptr);

  softmax_kernel<<<2048, 256, 0, stream>>>(Lb, alpha);

  // cfr = attn_w @ S, fused mix epilogue (in-place into S2)
  gemm_kernel<false, 2><<<dim3(32, 2, 8), 256, 0, stream>>>(
      Lb, S5, S2, nullptr, 256, 4096, 256, 1, STL, ST, ST,
      S0, S4, S2, lambd, beta);

  // final 1x1 conv -> d_out
  gemm_kernel<false, 0><<<dim3(32, 2, 8), 256, 0, stream>>>(
      out_w, S2, (float*)d_out, out_b, 256, 4096, 256, 1, 0L, ST, ST,
      nullptr, nullptr, nullptr, nullptr, nullptr);
}

// Round 4
// 730.327 us; speedup vs baseline: 1.4554x; 1.3675x over previous
//
#include <hip/hip_runtime.h>
#include <math.h>

#ifndef M_PI
#define M_PI 3.14159265358979323846
#endif

// Problem constants
constexpr int  NB   = 8;
constexpr int  CH   = 256;
constexpr long HW   = 4096;                 // 64*64
constexpr long SLOT = (long)NB * CH * HW;   // floats per [8,256,64,64] tensor
constexpr int  SPLITK = 8;                  // logits GEMM split factor

// ---------------------------------------------------------------------------
// Tiled SGEMM:  C[b] (MxN) = A[b] (MxK) * B[b] (KxN)   (or B is [N,K] if BT)
// Tile 128(M) x 128(N), BK=16, 256 threads, 8x8 microtile, reg prefetch.
// Bs uses octet-interleaved layout col(n) = (n>>3)*12 + (n&7) so the 16-lane
// b128 reads at 8-float logical stride are 2-way max (free) instead of 4-way.
// EPI 0: bias (nullable) + store.
// EPI 2: cfr->mix fused epilogue: mix = beta*(cfr*(Q - lam*V) + V) + (1-beta)*Fw
// EPI 3: split-K partial store: C + (b*nSplitK + ks)*cStride  (no atomics)
// ---------------------------------------------------------------------------
#define BCOL(n) ((((n) >> 3) * 12) + ((n) & 7))

template<bool BT, int EPI>
__global__ __launch_bounds__(256)
void gemm_kernel(const float* __restrict__ A, const float* __restrict__ B,
                 float* __restrict__ C, const float* __restrict__ bias,
                 int M, int N, int K, int nSplitK,
                 long aStride, long bStride, long cStride,
                 const float* __restrict__ qb, const float* __restrict__ vb,
                 const float* __restrict__ fwb,
                 const float* __restrict__ lambd, const float* __restrict__ beta)
{
  __shared__ __align__(16) float As[16][132];   // [k][m]
  __shared__ __align__(16) float Bs[16][192];   // [k][octet-swizzled n]
  const int tid = threadIdx.x;
  const int b   = blockIdx.z / nSplitK;
  const int ks  = blockIdx.z % nSplitK;
  const int kLen = K / nSplitK;
  const int k0b  = ks * kLen;
  const float* Ab = A + (long)b * aStride;
  const float* Bb = B + (long)b * bStride;
  float* Cb = (EPI == 3) ? (C + (long)(b * nSplitK + ks) * cStride)
                         : (C + (long)b * cStride);
  const int m0 = blockIdx.y * 128;
  const int n0 = blockIdx.x * 128;

  float acc[8][8];
#pragma unroll
  for (int i = 0; i < 8; ++i)
#pragma unroll
    for (int j = 0; j < 8; ++j) acc[i][j] = 0.f;

  const int tx = tid & 15;        // n octet
  const int ty = tid >> 4;        // m octet
  const int lr = tid >> 1;        // 0..127: A row (or B row for BT)
  const int lk = (tid & 1) * 8;   // k offset 0/8
  const int bn = (tid & 31) * 4;  // B col (!BT)
  const int bk = tid >> 5;        // 0..7   (!BT)
  const int colW = BCOL(bn);      // staging target col (!BT); bn&7 in {0,4}
  const int colT = BCOL(lr);      // staging target col (BT)

  // prefetch tile 0 into registers
  float4 pa0, pa1, pb0, pb1;
  {
    const float* ap = &Ab[(long)(m0 + lr) * K + k0b + lk];
    pa0 = *(const float4*)ap;
    pa1 = *(const float4*)(ap + 4);
    if (BT) {
      const float* bp = &Bb[(long)(n0 + lr) * K + k0b + lk];
      pb0 = *(const float4*)bp;
      pb1 = *(const float4*)(bp + 4);
    } else {
      pb0 = *(const float4*)&Bb[(long)(k0b + bk) * N + n0 + bn];
      pb1 = *(const float4*)&Bb[(long)(k0b + bk + 8) * N + n0 + bn];
    }
  }

  for (int kt = 0; kt < kLen; kt += 16) {
    As[lk+0][lr] = pa0.x; As[lk+1][lr] = pa0.y; As[lk+2][lr] = pa0.z; As[lk+3][lr] = pa0.w;
    As[lk+4][lr] = pa1.x; As[lk+5][lr] = pa1.y; As[lk+6][lr] = pa1.z; As[lk+7][lr] = pa1.w;
    if (BT) {
      Bs[lk+0][colT] = pb0.x; Bs[lk+1][colT] = pb0.y; Bs[lk+2][colT] = pb0.z; Bs[lk+3][colT] = pb0.w;
      Bs[lk+4][colT] = pb1.x; Bs[lk+5][colT] = pb1.y; Bs[lk+6][colT] = pb1.z; Bs[lk+7][colT] = pb1.w;
    } else {
      *(float4*)&Bs[bk][colW]     = pb0;
      *(float4*)&Bs[bk + 8][colW] = pb1;
    }
    __syncthreads();

    if (kt + 16 < kLen) {
      const int k0 = k0b + kt + 16;
      const float* ap = &Ab[(long)(m0 + lr) * K + k0 + lk];
      pa0 = *(const float4*)ap;
      pa1 = *(const float4*)(ap + 4);
      if (BT) {
        const float* bp = &Bb[(long)(n0 + lr) * K + k0 + lk];
        pb0 = *(const float4*)bp;
        pb1 = *(const float4*)(bp + 4);
      } else {
        pb0 = *(const float4*)&Bb[(long)(k0 + bk) * N + n0 + bn];
        pb1 = *(const float4*)&Bb[(long)(k0 + bk + 8) * N + n0 + bn];
      }
    }

#pragma unroll
    for (int kk = 0; kk < 16; ++kk) {
      const float4 a0 = *(const float4*)&As[kk][ty * 8];
      const float4 a1 = *(const float4*)&As[kk][ty * 8 + 4];
      const float4 b0 = *(const float4*)&Bs[kk][tx * 12];
      const float4 b1 = *(const float4*)&Bs[kk][tx * 12 + 4];
      const float av[8] = {a0.x, a0.y, a0.z, a0.w, a1.x, a1.y, a1.z, a1.w};
      const float bv[8] = {b0.x, b0.y, b0.z, b0.w, b1.x, b1.y, b1.z, b1.w};
#pragma unroll
      for (int i = 0; i < 8; ++i)
#pragma unroll
        for (int j = 0; j < 8; ++j)
          acc[i][j] = fmaf(av[i], bv[j], acc[i][j]);
    }
    __syncthreads();
  }

  if (EPI == 0 || EPI == 3) {
#pragma unroll
    for (int i = 0; i < 8; ++i) {
      const int row = m0 + ty * 8 + i;
      const float bb = (EPI == 0 && bias) ? bias[row] : 0.f;
      float4 r0, r1;
      r0.x = acc[i][0] + bb; r0.y = acc[i][1] + bb; r0.z = acc[i][2] + bb; r0.w = acc[i][3] + bb;
      r1.x = acc[i][4] + bb; r1.y = acc[i][5] + bb; r1.z = acc[i][6] + bb; r1.w = acc[i][7] + bb;
      float* p = &Cb[(long)row * N + n0 + tx * 8];
      *(float4*)p       = r0;
      *(float4*)(p + 4) = r1;
    }
  } else {
    const float lam = lambd[0], bet = beta[0];
#pragma unroll
    for (int i = 0; i < 8; ++i) {
      const int row = m0 + ty * 8 + i;
      const long off = (long)row * N + n0 + tx * 8;
      const long gi  = (long)b * cStride + off;
      const float4 q0 = *(const float4*)&qb[gi],  q1 = *(const float4*)&qb[gi + 4];
      const float4 v0 = *(const float4*)&vb[gi],  v1 = *(const float4*)&vb[gi + 4];
      const float4 f0 = *(const float4*)&fwb[gi], f1 = *(const float4*)&fwb[gi + 4];
      const float qv[8] = {q0.x,q0.y,q0.z,q0.w,q1.x,q1.y,q1.z,q1.w};
      const float vv[8] = {v0.x,v0.y,v0.z,v0.w,v1.x,v1.y,v1.z,v1.w};
      const float fv[8] = {f0.x,f0.y,f0.z,f0.w,f1.x,f1.y,f1.z,f1.w};
      float r[8];
#pragma unroll
      for (int j = 0; j < 8; ++j)
        r[j] = bet * (acc[i][j] * (qv[j] - lam * vv[j]) + vv[j]) + (1.f - bet) * fv[j];
      float* p = &Cb[off];
      *(float4*)p       = make_float4(r[0], r[1], r[2], r[3]);
      *(float4*)(p + 4) = make_float4(r[4], r[5], r[6], r[7]);
    }
  }
}

// ---------------------------------------------------------------------------
// pooled[b,c] = mean over HW of (FR + FN)
// ---------------------------------------------------------------------------
__global__ __launch_bounds__(256)
void pool_kernel(const float* __restrict__ FR, const float* __restrict__ FN,
                 float* __restrict__ pooled)
{
  __shared__ float red[256];
  const int bc = blockIdx.x, tid = threadIdx.x;
  const float4* a = (const float4*)(FR + (long)bc * HW);
  const float4* b = (const float4*)(FN + (long)bc * HW);
  float s = 0.f;
  for (int v = tid; v < 1024; v += 256) {
    const float4 x = a[v]; s += x.x + x.y + x.z + x.w;
    const float4 y = b[v]; s += y.x + y.y + y.z + y.w;
  }
  red[tid] = s; __syncthreads();
  for (int o = 128; o > 0; o >>= 1) {
    if (tid < o) red[tid] += red[tid + o];
    __syncthreads();
  }
  if (tid == 0) pooled[bc] = red[0] * (1.f / 4096.f);
}

// ---------------------------------------------------------------------------
// MLP (relu) + 2-way softmax -> attn2 [8,2,256]
// ---------------------------------------------------------------------------
__global__ __launch_bounds__(256)
void attn2_kernel(const float* __restrict__ pooled, const float* __restrict__ w1,
                  const float* __restrict__ w2, float* __restrict__ attn2)
{
  __shared__ float ps[256];
  __shared__ float hs[32];
  const int b = blockIdx.x, tid = threadIdx.x;
  ps[tid] = pooled[b * 256 + tid];
  __syncthreads();
  if (tid < 32) {
    float a = 0.f;
    for (int c = 0; c < 256; ++c) a += ps[c] * w1[tid * 256 + c];
    hs[tid] = fmaxf(a, 0.f);
  }
  __syncthreads();
  float a0 = 0.f, a1 = 0.f;
  for (int d = 0; d < 32; ++d) {
    const float h = hs[d];
    a0 += h * w2[tid * 32 + d];
    a1 += h * w2[(256 + tid) * 32 + d];
  }
  const float m  = fmaxf(a0, a1);
  const float e0 = expf(a0 - m), e1 = expf(a1 - m);
  const float inv = 1.f / (e0 + e1);
  attn2[b * 512 + tid]       = e0 * inv;
  attn2[b * 512 + 256 + tid] = e1 * inv;
}

// ---------------------------------------------------------------------------
// Fw = a0*FR + a1*FN
// ---------------------------------------------------------------------------
__global__ __launch_bounds__(256)
void fw_kernel(const float* __restrict__ FR, const float* __restrict__ FN,
               const float* __restrict__ attn2, float* __restrict__ FW)
{
  const int b = blockIdx.z, c = blockIdx.y;
  const float a0 = attn2[b * 512 + c];
  const float a1 = attn2[b * 512 + 256 + c];
  const long base4 = ((long)b * 256 + c) * 1024;
  const int i = blockIdx.x * 256 + threadIdx.x;
  const float4 r = ((const float4*)FR)[base4 + i];
  const float4 n = ((const float4*)FN)[base4 + i];
  float4 o;
  o.x = a0 * r.x + a1 * n.x;
  o.y = a0 * r.y + a1 * n.y;
  o.z = a0 * r.z + a1 * n.z;
  o.w = a0 * r.w + a1 * n.w;
  ((float4*)FW)[base4 + i] = o;
}

// ---------------------------------------------------------------------------
// Depthwise 3x3, SAME padding; optional index-reversed copy for logits GEMM.
// ---------------------------------------------------------------------------
__global__ __launch_bounds__(256)
void dw_kernel(const float* __restrict__ in, const float* __restrict__ w,
               const float* __restrict__ bias, float* __restrict__ out,
               float* __restrict__ out_rev)
{
  __shared__ float img[66][66];
  const int bc = blockIdx.x, tid = threadIdx.x;
  const int c = bc & 255;
  for (int v = tid; v < 66 * 66; v += 256) ((float*)img)[v] = 0.f;
  __syncthreads();
  const float4* in4 = (const float4*)(in + (long)bc * HW);
  for (int v = tid; v < 1024; v += 256) {
    const float4 x = in4[v];
    const int r = v >> 4, c0 = ((v & 15) << 2) + 1;
    img[r + 1][c0 + 0] = x.x;
    img[r + 1][c0 + 1] = x.y;
    img[r + 1][c0 + 2] = x.z;
    img[r + 1][c0 + 3] = x.w;
  }
  float wr[9];
#pragma unroll
  for (int j = 0; j < 9; ++j) wr[j] = w[c * 9 + j];
  const float bb = bias[c];
  __syncthreads();
  for (int p = tid; p < 4096; p += 256) {
    const int y = p >> 6, x = p & 63;
    float s = bb;
#pragma unroll
    for (int ky = 0; ky < 3; ++ky)
#pragma unroll
      for (int kx = 0; kx < 3; ++kx)
        s = fmaf(wr[ky * 3 + kx], img[y + ky][x + kx], s);
    out[(long)bc * HW + p] = s;
    if (out_rev)
      out_rev[(long)bc * HW + (((64 - y) & 63) << 6) + ((64 - x) & 63)] = s;
  }
}

// ---------------------------------------------------------------------------
// S[b,c] = circconv2(Q[b,c], K[b,c]) via ONE packed radix-4 FFT (see r2 notes)
// ---------------------------------------------------------------------------
#define SWA(r, c) (((r) << 6) | ((c) ^ (r)))
#define REV6(x)   ((((x) & 3) << 4) | ((x) & 12) | ((x) >> 4))

__device__ __forceinline__ float2 cmul(float2 a, float2 w) {
  return make_float2(a.x * w.x - a.y * w.y, a.x * w.y + a.y * w.x);
}
__device__ __forceinline__ float2 cmulc(float2 a, float2 w) {  // a * conj(w)
  return make_float2(a.x * w.x + a.y * w.y, a.y * w.x - a.x * w.y);
}

__global__ __launch_bounds__(256, 4)
void sconv_kernel(const float* __restrict__ Qg, const float* __restrict__ Kg,
                  float* __restrict__ Sg)
{
  __shared__ float Re[4096];
  __shared__ float Im[4096];
  __shared__ float2 twt[64];
  const int tid = threadIdx.x;
  const long base = (long)blockIdx.x * 4096;
  if (tid < 64) {
    float sn, cs;
    __sincosf(-2.f * (float)M_PI * (float)tid * (1.f / 64.f), &sn, &cs);
    twt[tid] = make_float2(cs, sn);
  }
  const float4* Q4 = (const float4*)(Qg + base);
  const float4* K4 = (const float4*)(Kg + base);
#pragma unroll
  for (int i = 0; i < 4; ++i) {
    const int v = tid + 256 * i;
    const float4 q = Q4[v], k = K4[v];
    const int r = v >> 4, w = v & 15;
    const int R  = REV6(r);
    const int cb = ((w & 3) << 2) | (w >> 2);
    Re[SWA(R, cb)]      = q.x;  Im[SWA(R, cb)]      = k.x;
    Re[SWA(R, cb + 16)] = q.y;  Im[SWA(R, cb + 16)] = k.y;
    Re[SWA(R, cb + 32)] = q.z;  Im[SWA(R, cb + 32)] = k.z;
    Re[SWA(R, cb + 48)] = q.w;  Im[SWA(R, cb + 48)] = k.w;
  }
  __syncthreads();

  const int lane = tid & 63;
  const int kb   = tid >> 6;

  for (int pass = 0; pass < 2; ++pass) {
    for (int s = 0; s < 3; ++s) {
      const int h  = 1 << (2 * s);
      const int us = 16 >> (2 * s);
#pragma unroll
      for (int q = 0; q < 4; ++q) {
        const int k = kb + 4 * q;
        const int j = k & (h - 1);
        const int g = k >> (2 * s);
        const int bse = g * 4 * h + j;
        const int p0 = bse, p1 = bse + h, p2 = bse + 2 * h, p3 = bse + 3 * h;
        const int a0 = pass ? SWA(p0, lane) : SWA(lane, p0);
        const int a1 = pass ? SWA(p1, lane) : SWA(lane, p1);
        const int a2 = pass ? SWA(p2, lane) : SWA(lane, p2);
        const int a3 = pass ? SWA(p3, lane) : SWA(lane, p3);
        float2 x0 = make_float2(Re[a0], Im[a0]);
        float2 x1 = make_float2(Re[a1], Im[a1]);
        float2 x2 = make_float2(Re[a2], Im[a2]);
        float2 x3 = make_float2(Re[a3], Im[a3]);
        const int e = j * us;
        x1 = cmul(x1, twt[e & 63]);
        x2 = cmul(x2, twt[(2 * e) & 63]);
        x3 = cmul(x3, twt[(3 * e) & 63]);
        const float2 t0 = make_float2(x0.x + x2.x, x0.y + x2.y);
        const float2 t1 = make_float2(x0.x - x2.x, x0.y - x2.y);
        const float2 t2 = make_float2(x1.x + x3.x, x1.y + x3.y);
        const float2 t3 = make_float2(x1.x - x3.x, x1.y - x3.y);
        Re[a0] = t0.x + t2.x;  Im[a0] = t0.y + t2.y;
        Re[a2] = t0.x - t2.x;  Im[a2] = t0.y - t2.y;
        Re[a1] = t1.x + t3.y;  Im[a1] = t1.y - t3.x;
        Re[a3] = t1.x - t3.y;  Im[a3] = t1.y + t3.x;
      }
      __syncthreads();
    }
  }

  float2 pv[16];
#pragma unroll
  for (int i = 0; i < 16; ++i) {
    const int n = tid + 256 * i;
    const int u = n >> 6, vv = n & 63;
    const int u2 = (64 - u) & 63, v2 = (64 - vv) & 63;
    const int az = SWA(u, vv), am = SWA(u2, v2);
    const float zr = Re[az], zi = Im[az];
    const float mr = Re[am], mi = Im[am];
    const float dre = zr * zr - zi * zi - mr * mr + mi * mi;
    const float dim = 2.f * (zr * zi + mr * mi);
    pv[i] = make_float2(0.25f * dim, -0.25f * dre);
  }
  __syncthreads();
#pragma unroll
  for (int i = 0; i < 16; ++i) {
    const int n = tid + 256 * i;
    const int az = SWA(n >> 6, n & 63);
    Re[az] = pv[i].x;
    Im[az] = pv[i].y;
  }
  __syncthreads();

  for (int pass = 0; pass < 2; ++pass) {
    for (int s = 2; s >= 0; --s) {
      const int h  = 1 << (2 * s);
      const int us = 16 >> (2 * s);
#pragma unroll
      for (int q = 0; q < 4; ++q) {
        const int k = kb + 4 * q;
        const int j = k & (h - 1);
        const int g = k >> (2 * s);
        const int bse = g * 4 * h + j;
        const int p0 = bse, p1 = bse + h, p2 = bse + 2 * h, p3 = bse + 3 * h;
        const int a0 = pass ? SWA(lane, p0) : SWA(p0, lane);
        const int a1 = pass ? SWA(lane, p1) : SWA(p1, lane);
        const int a2 = pass ? SWA(lane, p2) : SWA(p2, lane);
        const int a3 = pass ? SWA(lane, p3) : SWA(p3, lane);
        const float2 x0 = make_float2(Re[a0], Im[a0]);
        const float2 x1 = make_float2(Re[a1], Im[a1]);
        const float2 x2 = make_float2(Re[a2], Im[a2]);
        const float2 x3 = make_float2(Re[a3], Im[a3]);
        const float2 t0 = make_float2(x0.x + x2.x, x0.y + x2.y);
        const float2 t1 = make_float2(x0.x - x2.x, x0.y - x2.y);
        const float2 t2 = make_float2(x1.x + x3.x, x1.y + x3.y);
        const float2 t3 = make_float2(x1.x - x3.x, x1.y - x3.y);
        const float2 y0 = make_float2(t0.x + t2.x, t0.y + t2.y);
        float2 y2 = make_float2(t0.x - t2.x, t0.y - t2.y);
        float2 y1 = make_float2(t1.x - t3.y, t1.y + t3.x);
        float2 y3 = make_float2(t1.x + t3.y, t1.y - t3.x);
        const int e = j * us;
        y1 = cmulc(y1, twt[e & 63]);
        y2 = cmulc(y2, twt[(2 * e) & 63]);
        y3 = cmulc(y3, twt[(3 * e) & 63]);
        Re[a0] = y0.x;  Im[a0] = y0.y;
        Re[a1] = y1.x;  Im[a1] = y1.y;
        Re[a2] = y2.x;  Im[a2] = y2.y;
        Re[a3] = y3.x;  Im[a3] = y3.y;
      }
      __syncthreads();
    }
  }

  float4* S4 = (float4*)(Sg + base);
#pragma unroll
  for (int i = 0; i < 4; ++i) {
    const int v = tid + 256 * i;
    const int y = v >> 4, w = v & 15;
    const int Rr = REV6(y);
    const int cb = ((w & 3) << 2) | (w >> 2);
    float4 o;
    o.x = Re[SWA(Rr, cb)]      * (1.f / 4096.f);
    o.y = Re[SWA(Rr, cb + 16)] * (1.f / 4096.f);
    o.z = Re[SWA(Rr, cb + 32)] * (1.f / 4096.f);
    o.w = Re[SWA(Rr, cb + 48)] * (1.f / 4096.f);
    S4[v] = o;
  }
}

// ---------------------------------------------------------------------------
// Fused split-K reduce + row softmax: L[b,c,:] = softmax(|sum_s Lp[b,s,c,:]|*sc)
// One block per (b,c) row; 256 threads = 256 columns.
// ---------------------------------------------------------------------------
__global__ __launch_bounds__(256)
void softmax_kernel(const float* __restrict__ Lp, float* __restrict__ L,
                    const float* __restrict__ alpha)
{
  __shared__ float red[256];
  const int row = blockIdx.x, tid = threadIdx.x;   // row = b*256 + c
  const int b = row >> 8, c = row & 255;
  const float sc = 4096.f / alpha[0];
  float acc = 0.f;
#pragma unroll
  for (int s = 0; s < SPLITK; ++s)
    acc += Lp[((long)(b * SPLITK + s) * 65536) + (long)c * 256 + tid];
  const float v = fabsf(acc) * sc;
  red[tid] = v; __syncthreads();
  for (int o = 128; o > 0; o >>= 1) {
    if (tid < o) red[tid] = fmaxf(red[tid], red[tid + o]);
    __syncthreads();
  }
  const float mx = red[0];
  __syncthreads();
  const float e = expf(v - mx);
  red[tid] = e; __syncthreads();
  for (int o = 128; o > 0; o >>= 1) {
    if (tid < o) red[tid] += red[tid + o];
    __syncthreads();
  }
  L[(long)row * 256 + tid] = e / red[0];
}

// ---------------------------------------------------------------------------
extern "C" void kernel_launch(void* const* d_in, const int* in_sizes, int n_in,
                              void* d_out, int out_size, void* d_ws, size_t ws_size,
                              hipStream_t stream)
{
  const float* x1       = (const float*)d_in[0];
  const float* x2       = (const float*)d_in[1];
  const float* conv_r_w = (const float*)d_in[2];
  const float* conv_r_b = (const float*)d_in[3];
  const float* conv_n_w = (const float*)d_in[4];
  const float* conv_n_b = (const float*)d_in[5];
  const float* mlp_w1   = (const float*)d_in[6];
  const float* mlp_w2   = (const float*)d_in[7];
  const float* pq_w     = (const float*)d_in[8];
  const float* pq_b     = (const float*)d_in[9];
  const float* dq_w     = (const float*)d_in[10];
  const float* dq_b     = (const float*)d_in[11];
  const float* pk_w     = (const float*)d_in[12];
  const float* pk_b     = (const float*)d_in[13];
  const float* dk_w     = (const float*)d_in[14];
  const float* dk_b     = (const float*)d_in[15];
  const float* pv_w     = (const float*)d_in[16];
  const float* pv_b     = (const float*)d_in[17];
  const float* dv_w     = (const float*)d_in[18];
  const float* dv_b     = (const float*)d_in[19];
  const float* out_w    = (const float*)d_in[20];
  const float* out_b    = (const float*)d_in[21];
  const float* alpha    = (const float*)d_in[22];
  const float* lambd    = (const float*)d_in[23];
  const float* beta     = (const float*)d_in[24];

  float* s = (float*)d_ws;
  float* S0 = s;             // FR  -> Q
  float* S1 = s + SLOT;      // FN  -> K
  float* S2 = s + 2 * SLOT;  // Fw  -> mix (in-place)
  float* S3 = s + 3 * SLOT;  // Pq  -> Krev
  float* S4 = s + 4 * SLOT;  // Pk  -> V
  float* S5 = s + 5 * SLOT;  // Pv  -> S
  float* Lp     = s + 6 * SLOT;                       // [8][SPLITK][256][256]
  float* Lb     = Lp + (long)8 * SPLITK * 256 * 256;  // [8][256][256]
  float* pooled = Lb + (long)8 * 256 * 256;
  float* attn2  = pooled + 2048;

  const size_t needed =
      (size_t)(6 * SLOT + (long)8 * SPLITK * 65536 + 8L * 65536 + 2048 + 4096)
      * sizeof(float);
  if (ws_size < needed) return;

  const long ST  = (long)CH * HW;   // 1048576
  const long ST2 = (long)128 * HW;
  const long STL = (long)256 * 256;

  // FR = conv_r(x1), FN = conv_n(x2)
  gemm_kernel<false, 0><<<dim3(32, 2, 8), 256, 0, stream>>>(
      conv_r_w, x1, S0, conv_r_b, 256, 4096, 256, 1, 0L, ST, ST,
      nullptr, nullptr, nullptr, nullptr, nullptr);
  gemm_kernel<false, 0><<<dim3(32, 2, 8), 256, 0, stream>>>(
      conv_n_w, x2, S1, conv_n_b, 256, 4096, 128, 1, 0L, ST2, ST,
      nullptr, nullptr, nullptr, nullptr, nullptr);

  pool_kernel<<<2048, 256, 0, stream>>>(S0, S1, pooled);
  attn2_kernel<<<8, 256, 0, stream>>>(pooled, mlp_w1, mlp_w2, attn2);
  fw_kernel<<<dim3(4, 256, 8), 256, 0, stream>>>(S0, S1, attn2, S2);

  // Pq/Pk/Pv = 1x1 convs of Fw
  gemm_kernel<false, 0><<<dim3(32, 2, 8), 256, 0, stream>>>(
      pq_w, S2, S3, pq_b, 256, 4096, 256, 1, 0L, ST, ST,
      nullptr, nullptr, nullptr, nullptr, nullptr);
  gemm_kernel<false, 0><<<dim3(32, 2, 8), 256, 0, stream>>>(
      pk_w, S2, S4, pk_b, 256, 4096, 256, 1, 0L, ST, ST,
      nullptr, nullptr, nullptr, nullptr, nullptr);
  gemm_kernel<false, 0><<<dim3(32, 2, 8), 256, 0, stream>>>(
      pv_w, S2, S5, pv_b, 256, 4096, 256, 1, 0L, ST, ST,
      nullptr, nullptr, nullptr, nullptr, nullptr);

  // depthwise 3x3
  dw_kernel<<<2048, 256, 0, stream>>>(S3, dq_w, dq_b, S0, nullptr);  // Q  -> S0
  dw_kernel<<<2048, 256, 0, stream>>>(S4, dk_w, dk_b, S1, S3);       // K  -> S1, Krev -> S3
  dw_kernel<<<2048, 256, 0, stream>>>(S5, dv_w, dv_b, S4, nullptr);  // V  -> S4

  // S = circconv2(Q, K) per channel (packed single-FFT version)
  sconv_kernel<<<2048, 256, 0, stream>>>(S0, S1, S5);                // S -> S5

  // attn logits: Lp[b,s] = Q . Krev over k-span s  (split-K partials, no atomics)
  gemm_kernel<true, 3><<<dim3(2, 2, 8 * SPLITK), 256, 0, stream>>>(
      S0, S3, Lp, nullptr, 256, 256, 4096, SPLITK, ST, ST, STL,
      nullptr, nullptr, nullptr, nullptr, nullptr);

  // fused split-K reduce + softmax -> Lb
  softmax_kernel<<<2048, 256, 0, stream>>>(Lp, Lb, alpha);

  // cfr = attn_w @ S, fused mix epilogue (in-place into S2)
  gemm_kernel<false, 2><<<dim3(32, 2, 8), 256, 0, stream>>>(
      Lb, S5, S2, nullptr, 256, 4096, 256, 1, STL, ST, ST,
      S0, S4, S2, lambd, beta);

  // final 1x1 conv -> d_out
  gemm_kernel<false, 0><<<dim3(32, 2, 8), 256, 0, stream>>>(
      out_w, S2, (float*)d_out, out_b, 256, 4096, 256, 1, 0L, ST, ST,
      nullptr, nullptr, nullptr, nullptr, nullptr);
}

// Round 5
// 517.102 us; speedup vs baseline: 2.0555x; 1.4123x over previous
//
#include <hip/hip_runtime.h>
#include <math.h>

#ifndef M_PI
#define M_PI 3.14159265358979323846
#endif

// Problem constants
constexpr int  NB   = 8;
constexpr int  CH   = 256;
constexpr long HW   = 4096;                 // 64*64
constexpr long SLOT = (long)NB * CH * HW;   // floats per [8,256,64,64] tensor
constexpr int  SPLITK = 8;                  // logits GEMM split factor

// ===========================================================================
// MFMA split-bf16 GEMM: C[b](256 x 4096) = A[b](256 x K) * B[b](K x 4096)
// A,B fp32 in memory; staged to LDS as bf16 hi/lo pairs; 3-product emulation
//   C ~= Ah*Bh + Ah*Bl + Al*Bh   (error ~2^-17 relative)
// Tile 128x128, BK=32, 256 threads = 4 waves in 2x2; wave = 4x4 mfma 16x16x32.
// LDS rows padded to 48 bf16 (96B) -> 16B-aligned b128 frag reads, uniform banks.
// EPI 0: +bias store. EPI 2: mix = beta*(cfr*(Q-lam*V)+V)+(1-beta)*Fw
// ===========================================================================
typedef short bf16x8 __attribute__((ext_vector_type(8)));
typedef float f32x4  __attribute__((ext_vector_type(4)));

__device__ __forceinline__ unsigned bfpair(float x, float y) {
  // pack trunc-bf16(x) in low16, trunc-bf16(y) in high16
  return (__float_as_uint(x) >> 16) | (__float_as_uint(y) & 0xFFFF0000u);
}
__device__ __forceinline__ float rne_hi(float x) {
  unsigned u = __float_as_uint(x);
  unsigned r = (u + 0x7FFFu + ((u >> 16) & 1u)) & 0xFFFF0000u;
  return __uint_as_float(r);
}

template<int EPI>
__global__ __launch_bounds__(256)
void gemm_mfma(const float* __restrict__ A, const float* __restrict__ B,
               float* __restrict__ C, const float* __restrict__ bias,
               int K, long aStride, long bStride, long cStride,
               const float* __restrict__ qb, const float* __restrict__ vb,
               const float* __restrict__ fwb,
               const float* __restrict__ lambd, const float* __restrict__ beta)
{
  constexpr int N = 4096;
  __shared__ __align__(16) unsigned short sAh[128 * 48];
  __shared__ __align__(16) unsigned short sAl[128 * 48];
  __shared__ __align__(16) unsigned short sBh[128 * 48];
  __shared__ __align__(16) unsigned short sBl[128 * 48];

  const int tid = threadIdx.x;
  const int b   = blockIdx.z;
  const int m0  = blockIdx.y * 128;
  const int n0  = blockIdx.x * 128;
  const float* Ab = A + (long)b * aStride;
  const float* Bb = B + (long)b * bStride;
  float* Cb = C + (long)b * cStride;

  // staging assignments
  const int ar = tid >> 1;               // A row 0..127
  const int ak = (tid & 1) * 16;         // A k-half
  const int aBase = ar * 48 + ak;
  const int bn = tid & 127;              // B col (pixel) 0..127
  const int bk = (tid >> 7) * 16;        // B k-half
  const int bBase = bn * 48 + bk;

  // compute assignments
  const int wv = tid >> 6, lane = tid & 63;
  const int wy = wv >> 1, wx = wv & 1;
  const int quad = lane >> 4, l15 = lane & 15;

  f32x4 acc[4][4];
#pragma unroll
  for (int i = 0; i < 4; ++i)
#pragma unroll
    for (int j = 0; j < 4; ++j) acc[i][j] = (f32x4){0.f, 0.f, 0.f, 0.f};

  // prefetch tile 0
  float4 ra[4];
  float  rb[16];
  {
    const float* ap = Ab + (long)(m0 + ar) * K + ak;
#pragma unroll
    for (int i = 0; i < 4; ++i) ra[i] = *(const float4*)(ap + i * 4);
    const float* bp = Bb + (long)bk * N + n0 + bn;
#pragma unroll
    for (int i = 0; i < 16; ++i) rb[i] = bp[(long)i * N];
  }

  for (int kt = 0; kt < K; kt += 32) {
    // convert + commit staged registers to LDS
    {
      float v[16] = {ra[0].x, ra[0].y, ra[0].z, ra[0].w,
                     ra[1].x, ra[1].y, ra[1].z, ra[1].w,
                     ra[2].x, ra[2].y, ra[2].z, ra[2].w,
                     ra[3].x, ra[3].y, ra[3].z, ra[3].w};
      float h[16], l[16];
#pragma unroll
      for (int e = 0; e < 16; ++e) { h[e] = rne_hi(v[e]); l[e] = v[e] - h[e]; }
      uint4 u;
      u.x = bfpair(h[0], h[1]);  u.y = bfpair(h[2], h[3]);
      u.z = bfpair(h[4], h[5]);  u.w = bfpair(h[6], h[7]);
      *(uint4*)&sAh[aBase] = u;
      u.x = bfpair(h[8], h[9]);  u.y = bfpair(h[10], h[11]);
      u.z = bfpair(h[12], h[13]); u.w = bfpair(h[14], h[15]);
      *(uint4*)&sAh[aBase + 8] = u;
      u.x = bfpair(l[0], l[1]);  u.y = bfpair(l[2], l[3]);
      u.z = bfpair(l[4], l[5]);  u.w = bfpair(l[6], l[7]);
      *(uint4*)&sAl[aBase] = u;
      u.x = bfpair(l[8], l[9]);  u.y = bfpair(l[10], l[11]);
      u.z = bfpair(l[12], l[13]); u.w = bfpair(l[14], l[15]);
      *(uint4*)&sAl[aBase + 8] = u;
    }
    {
      float h[16], l[16];
#pragma unroll
      for (int e = 0; e < 16; ++e) { h[e] = rne_hi(rb[e]); l[e] = rb[e] - h[e]; }
      uint4 u;
      u.x = bfpair(h[0], h[1]);  u.y = bfpair(h[2], h[3]);
      u.z = bfpair(h[4], h[5]);  u.w = bfpair(h[6], h[7]);
      *(uint4*)&sBh[bBase] = u;
      u.x = bfpair(h[8], h[9]);  u.y = bfpair(h[10], h[11]);
      u.z = bfpair(h[12], h[13]); u.w = bfpair(h[14], h[15]);
      *(uint4*)&sBh[bBase + 8] = u;
      u.x = bfpair(l[0], l[1]);  u.y = bfpair(l[2], l[3]);
      u.z = bfpair(l[4], l[5]);  u.w = bfpair(l[6], l[7]);
      *(uint4*)&sBl[bBase] = u;
      u.x = bfpair(l[8], l[9]);  u.y = bfpair(l[10], l[11]);
      u.z = bfpair(l[12], l[13]); u.w = bfpair(l[14], l[15]);
      *(uint4*)&sBl[bBase + 8] = u;
    }
    __syncthreads();

    // issue next tile's global loads (overlap with MFMA below)
    if (kt + 32 < K) {
      const float* ap = Ab + (long)(m0 + ar) * K + kt + 32 + ak;
#pragma unroll
      for (int i = 0; i < 4; ++i) ra[i] = *(const float4*)(ap + i * 4);
      const float* bp = Bb + (long)(kt + 32 + bk) * N + n0 + bn;
#pragma unroll
      for (int i = 0; i < 16; ++i) rb[i] = bp[(long)i * N];
    }

    // fragments + 48 MFMA
    bf16x8 ah[4], al[4];
#pragma unroll
    for (int i = 0; i < 4; ++i) {
      const int idx = (wy * 64 + i * 16 + l15) * 48 + quad * 8;
      ah[i] = *(const bf16x8*)&sAh[idx];
      al[i] = *(const bf16x8*)&sAl[idx];
    }
#pragma unroll
    for (int j = 0; j < 4; ++j) {
      const int idx = (wx * 64 + j * 16 + l15) * 48 + quad * 8;
      const bf16x8 bh = *(const bf16x8*)&sBh[idx];
      const bf16x8 bl = *(const bf16x8*)&sBl[idx];
#pragma unroll
      for (int i = 0; i < 4; ++i) {
        acc[i][j] = __builtin_amdgcn_mfma_f32_16x16x32_bf16(ah[i], bh, acc[i][j], 0, 0, 0);
        acc[i][j] = __builtin_amdgcn_mfma_f32_16x16x32_bf16(ah[i], bl, acc[i][j], 0, 0, 0);
        acc[i][j] = __builtin_amdgcn_mfma_f32_16x16x32_bf16(al[i], bh, acc[i][j], 0, 0, 0);
      }
    }
    __syncthreads();
  }

  // epilogue
  if (EPI == 0) {
#pragma unroll
    for (int i = 0; i < 4; ++i) {
#pragma unroll
      for (int r = 0; r < 4; ++r) {
        const int row = m0 + wy * 64 + i * 16 + quad * 4 + r;
        const float bb = bias ? bias[row] : 0.f;
#pragma unroll
        for (int j = 0; j < 4; ++j) {
          const int col = n0 + wx * 64 + j * 16 + l15;
          Cb[(long)row * N + col] = acc[i][j][r] + bb;
        }
      }
    }
  } else {
    const float lam = lambd[0], bet = beta[0];
#pragma unroll
    for (int i = 0; i < 4; ++i) {
#pragma unroll
      for (int r = 0; r < 4; ++r) {
        const int row = m0 + wy * 64 + i * 16 + quad * 4 + r;
#pragma unroll
        for (int j = 0; j < 4; ++j) {
          const int col = n0 + wx * 64 + j * 16 + l15;
          const long off = (long)row * N + col;
          const long gi  = (long)b * cStride + off;
          const float q = qb[gi], v = vb[gi], f = fwb[gi];
          Cb[off] = bet * (acc[i][j][r] * (q - lam * v) + v) + (1.f - bet) * f;
        }
      }
    }
  }
}

// ---------------------------------------------------------------------------
// Vector SGEMM (kept for the BT logits GEMM only). Tile 128x128, BK=16,
// 8x8 microtile, octet-interleaved Bs. EPI 3: split-K partial store.
// ---------------------------------------------------------------------------
#define BCOL(n) ((((n) >> 3) * 12) + ((n) & 7))

template<bool BT, int EPI>
__global__ __launch_bounds__(256)
void gemm_kernel(const float* __restrict__ A, const float* __restrict__ B,
                 float* __restrict__ C, const float* __restrict__ bias,
                 int M, int N, int K, int nSplitK,
                 long aStride, long bStride, long cStride)
{
  __shared__ __align__(16) float As[16][132];
  __shared__ __align__(16) float Bs[16][192];
  const int tid = threadIdx.x;
  const int b   = blockIdx.z / nSplitK;
  const int ks  = blockIdx.z % nSplitK;
  const int kLen = K / nSplitK;
  const int k0b  = ks * kLen;
  const float* Ab = A + (long)b * aStride;
  const float* Bb = B + (long)b * bStride;
  float* Cb = (EPI == 3) ? (C + (long)(b * nSplitK + ks) * cStride)
                         : (C + (long)b * cStride);
  const int m0 = blockIdx.y * 128;
  const int n0 = blockIdx.x * 128;

  float acc[8][8];
#pragma unroll
  for (int i = 0; i < 8; ++i)
#pragma unroll
    for (int j = 0; j < 8; ++j) acc[i][j] = 0.f;

  const int tx = tid & 15;
  const int ty = tid >> 4;
  const int lr = tid >> 1;
  const int lk = (tid & 1) * 8;
  const int bn = (tid & 31) * 4;
  const int bk = tid >> 5;
  const int colW = BCOL(bn);
  const int colT = BCOL(lr);

  float4 pa0, pa1, pb0, pb1;
  {
    const float* ap = &Ab[(long)(m0 + lr) * K + k0b + lk];
    pa0 = *(const float4*)ap;
    pa1 = *(const float4*)(ap + 4);
    if (BT) {
      const float* bp = &Bb[(long)(n0 + lr) * K + k0b + lk];
      pb0 = *(const float4*)bp;
      pb1 = *(const float4*)(bp + 4);
    } else {
      pb0 = *(const float4*)&Bb[(long)(k0b + bk) * N + n0 + bn];
      pb1 = *(const float4*)&Bb[(long)(k0b + bk + 8) * N + n0 + bn];
    }
  }

  for (int kt = 0; kt < kLen; kt += 16) {
    As[lk+0][lr] = pa0.x; As[lk+1][lr] = pa0.y; As[lk+2][lr] = pa0.z; As[lk+3][lr] = pa0.w;
    As[lk+4][lr] = pa1.x; As[lk+5][lr] = pa1.y; As[lk+6][lr] = pa1.z; As[lk+7][lr] = pa1.w;
    if (BT) {
      Bs[lk+0][colT] = pb0.x; Bs[lk+1][colT] = pb0.y; Bs[lk+2][colT] = pb0.z; Bs[lk+3][colT] = pb0.w;
      Bs[lk+4][colT] = pb1.x; Bs[lk+5][colT] = pb1.y; Bs[lk+6][colT] = pb1.z; Bs[lk+7][colT] = pb1.w;
    } else {
      *(float4*)&Bs[bk][colW]     = pb0;
      *(float4*)&Bs[bk + 8][colW] = pb1;
    }
    __syncthreads();

    if (kt + 16 < kLen) {
      const int k0 = k0b + kt + 16;
      const float* ap = &Ab[(long)(m0 + lr) * K + k0 + lk];
      pa0 = *(const float4*)ap;
      pa1 = *(const float4*)(ap + 4);
      if (BT) {
        const float* bp = &Bb[(long)(n0 + lr) * K + k0 + lk];
        pb0 = *(const float4*)bp;
        pb1 = *(const float4*)(bp + 4);
      } else {
        pb0 = *(const float4*)&Bb[(long)(k0 + bk) * N + n0 + bn];
        pb1 = *(const float4*)&Bb[(long)(k0 + bk + 8) * N + n0 + bn];
      }
    }

#pragma unroll
    for (int kk = 0; kk < 16; ++kk) {
      const float4 a0 = *(const float4*)&As[kk][ty * 8];
      const float4 a1 = *(const float4*)&As[kk][ty * 8 + 4];
      const float4 b0 = *(const float4*)&Bs[kk][tx * 12];
      const float4 b1 = *(const float4*)&Bs[kk][tx * 12 + 4];
      const float av[8] = {a0.x, a0.y, a0.z, a0.w, a1.x, a1.y, a1.z, a1.w};
      const float bv[8] = {b0.x, b0.y, b0.z, b0.w, b1.x, b1.y, b1.z, b1.w};
#pragma unroll
      for (int i = 0; i < 8; ++i)
#pragma unroll
        for (int j = 0; j < 8; ++j)
          acc[i][j] = fmaf(av[i], bv[j], acc[i][j]);
    }
    __syncthreads();
  }

#pragma unroll
  for (int i = 0; i < 8; ++i) {
    const int row = m0 + ty * 8 + i;
    const float bb = (EPI == 0 && bias) ? bias[row] : 0.f;
    float4 r0, r1;
    r0.x = acc[i][0] + bb; r0.y = acc[i][1] + bb; r0.z = acc[i][2] + bb; r0.w = acc[i][3] + bb;
    r1.x = acc[i][4] + bb; r1.y = acc[i][5] + bb; r1.z = acc[i][6] + bb; r1.w = acc[i][7] + bb;
    float* p = &Cb[(long)row * N + n0 + tx * 8];
    *(float4*)p       = r0;
    *(float4*)(p + 4) = r1;
  }
}

// ---------------------------------------------------------------------------
// pooled[b,c] = mean over HW of (FR + FN)
// ---------------------------------------------------------------------------
__global__ __launch_bounds__(256)
void pool_kernel(const float* __restrict__ FR, const float* __restrict__ FN,
                 float* __restrict__ pooled)
{
  __shared__ float red[256];
  const int bc = blockIdx.x, tid = threadIdx.x;
  const float4* a = (const float4*)(FR + (long)bc * HW);
  const float4* b = (const float4*)(FN + (long)bc * HW);
  float s = 0.f;
  for (int v = tid; v < 1024; v += 256) {
    const float4 x = a[v]; s += x.x + x.y + x.z + x.w;
    const float4 y = b[v]; s += y.x + y.y + y.z + y.w;
  }
  red[tid] = s; __syncthreads();
  for (int o = 128; o > 0; o >>= 1) {
    if (tid < o) red[tid] += red[tid + o];
    __syncthreads();
  }
  if (tid == 0) pooled[bc] = red[0] * (1.f / 4096.f);
}

// ---------------------------------------------------------------------------
// MLP (relu) + 2-way softmax -> attn2 [8,2,256]
// ---------------------------------------------------------------------------
__global__ __launch_bounds__(256)
void attn2_kernel(const float* __restrict__ pooled, const float* __restrict__ w1,
                  const float* __restrict__ w2, float* __restrict__ attn2)
{
  __shared__ float ps[256];
  __shared__ float hs[32];
  const int b = blockIdx.x, tid = threadIdx.x;
  ps[tid] = pooled[b * 256 + tid];
  __syncthreads();
  if (tid < 32) {
    float a = 0.f;
    for (int c = 0; c < 256; ++c) a += ps[c] * w1[tid * 256 + c];
    hs[tid] = fmaxf(a, 0.f);
  }
  __syncthreads();
  float a0 = 0.f, a1 = 0.f;
  for (int d = 0; d < 32; ++d) {
    const float h = hs[d];
    a0 += h * w2[tid * 32 + d];
    a1 += h * w2[(256 + tid) * 32 + d];
  }
  const float m  = fmaxf(a0, a1);
  const float e0 = expf(a0 - m), e1 = expf(a1 - m);
  const float inv = 1.f / (e0 + e1);
  attn2[b * 512 + tid]       = e0 * inv;
  attn2[b * 512 + 256 + tid] = e1 * inv;
}

// ---------------------------------------------------------------------------
// Fw = a0*FR + a1*FN
// ---------------------------------------------------------------------------
__global__ __launch_bounds__(256)
void fw_kernel(const float* __restrict__ FR, const float* __restrict__ FN,
               const float* __restrict__ attn2, float* __restrict__ FW)
{
  const int b = blockIdx.z, c = blockIdx.y;
  const float a0 = attn2[b * 512 + c];
  const float a1 = attn2[b * 512 + 256 + c];
  const long base4 = ((long)b * 256 + c) * 1024;
  const int i = blockIdx.x * 256 + threadIdx.x;
  const float4 r = ((const float4*)FR)[base4 + i];
  const float4 n = ((const float4*)FN)[base4 + i];
  float4 o;
  o.x = a0 * r.x + a1 * n.x;
  o.y = a0 * r.y + a1 * n.y;
  o.z = a0 * r.z + a1 * n.z;
  o.w = a0 * r.w + a1 * n.w;
  ((float4*)FW)[base4 + i] = o;
}

// ---------------------------------------------------------------------------
// Depthwise 3x3, SAME padding; optional index-reversed copy for logits GEMM.
// ---------------------------------------------------------------------------
__global__ __launch_bounds__(256)
void dw_kernel(const float* __restrict__ in, const float* __restrict__ w,
               const float* __restrict__ bias, float* __restrict__ out,
               float* __restrict__ out_rev)
{
  __shared__ float img[66][66];
  const int bc = blockIdx.x, tid = threadIdx.x;
  const int c = bc & 255;
  for (int v = tid; v < 66 * 66; v += 256) ((float*)img)[v] = 0.f;
  __syncthreads();
  const float4* in4 = (const float4*)(in + (long)bc * HW);
  for (int v = tid; v < 1024; v += 256) {
    const float4 x = in4[v];
    const int r = v >> 4, c0 = ((v & 15) << 2) + 1;
    img[r + 1][c0 + 0] = x.x;
    img[r + 1][c0 + 1] = x.y;
    img[r + 1][c0 + 2] = x.z;
    img[r + 1][c0 + 3] = x.w;
  }
  float wr[9];
#pragma unroll
  for (int j = 0; j < 9; ++j) wr[j] = w[c * 9 + j];
  const float bb = bias[c];
  __syncthreads();
  for (int p = tid; p < 4096; p += 256) {
    const int y = p >> 6, x = p & 63;
    float s = bb;
#pragma unroll
    for (int ky = 0; ky < 3; ++ky)
#pragma unroll
      for (int kx = 0; kx < 3; ++kx)
        s = fmaf(wr[ky * 3 + kx], img[y + ky][x + kx], s);
    out[(long)bc * HW + p] = s;
    if (out_rev)
      out_rev[(long)bc * HW + (((64 - y) & 63) << 6) + ((64 - x) & 63)] = s;
  }
}

// ---------------------------------------------------------------------------
// S[b,c] = circconv2(Q[b,c], K[b,c]) via ONE packed radix-4 FFT (see r2 notes)
// ---------------------------------------------------------------------------
#define SWA(r, c) (((r) << 6) | ((c) ^ (r)))
#define REV6(x)   ((((x) & 3) << 4) | ((x) & 12) | ((x) >> 4))

__device__ __forceinline__ float2 cmul(float2 a, float2 w) {
  return make_float2(a.x * w.x - a.y * w.y, a.x * w.y + a.y * w.x);
}
__device__ __forceinline__ float2 cmulc(float2 a, float2 w) {
  return make_float2(a.x * w.x + a.y * w.y, a.y * w.x - a.x * w.y);
}

__global__ __launch_bounds__(256, 4)
void sconv_kernel(const float* __restrict__ Qg, const float* __restrict__ Kg,
                  float* __restrict__ Sg)
{
  __shared__ float Re[4096];
  __shared__ float Im[4096];
  __shared__ float2 twt[64];
  const int tid = threadIdx.x;
  const long base = (long)blockIdx.x * 4096;
  if (tid < 64) {
    float sn, cs;
    __sincosf(-2.f * (float)M_PI * (float)tid * (1.f / 64.f), &sn, &cs);
    twt[tid] = make_float2(cs, sn);
  }
  const float4* Q4 = (const float4*)(Qg + base);
  const float4* K4 = (const float4*)(Kg + base);
#pragma unroll
  for (int i = 0; i < 4; ++i) {
    const int v = tid + 256 * i;
    const float4 q = Q4[v], k = K4[v];
    const int r = v >> 4, w = v & 15;
    const int R  = REV6(r);
    const int cb = ((w & 3) << 2) | (w >> 2);
    Re[SWA(R, cb)]      = q.x;  Im[SWA(R, cb)]      = k.x;
    Re[SWA(R, cb + 16)] = q.y;  Im[SWA(R, cb + 16)] = k.y;
    Re[SWA(R, cb + 32)] = q.z;  Im[SWA(R, cb + 32)] = k.z;
    Re[SWA(R, cb + 48)] = q.w;  Im[SWA(R, cb + 48)] = k.w;
  }
  __syncthreads();

  const int lane = tid & 63;
  const int kb   = tid >> 6;

  for (int pass = 0; pass < 2; ++pass) {
    for (int s = 0; s < 3; ++s) {
      const int h  = 1 << (2 * s);
      const int us = 16 >> (2 * s);
#pragma unroll
      for (int q = 0; q < 4; ++q) {
        const int k = kb + 4 * q;
        const int j = k & (h - 1);
        const int g = k >> (2 * s);
        const int bse = g * 4 * h + j;
        const int p0 = bse, p1 = bse + h, p2 = bse + 2 * h, p3 = bse + 3 * h;
        const int a0 = pass ? SWA(p0, lane) : SWA(lane, p0);
        const int a1 = pass ? SWA(p1, lane) : SWA(lane, p1);
        const int a2 = pass ? SWA(p2, lane) : SWA(lane, p2);
        const int a3 = pass ? SWA(p3, lane) : SWA(lane, p3);
        float2 x0 = make_float2(Re[a0], Im[a0]);
        float2 x1 = make_float2(Re[a1], Im[a1]);
        float2 x2 = make_float2(Re[a2], Im[a2]);
        float2 x3 = make_float2(Re[a3], Im[a3]);
        const int e = j * us;
        x1 = cmul(x1, twt[e & 63]);
        x2 = cmul(x2, twt[(2 * e) & 63]);
        x3 = cmul(x3, twt[(3 * e) & 63]);
        const float2 t0 = make_float2(x0.x + x2.x, x0.y + x2.y);
        const float2 t1 = make_float2(x0.x - x2.x, x0.y - x2.y);
        const float2 t2 = make_float2(x1.x + x3.x, x1.y + x3.y);
        const float2 t3 = make_float2(x1.x - x3.x, x1.y - x3.y);
        Re[a0] = t0.x + t2.x;  Im[a0] = t0.y + t2.y;
        Re[a2] = t0.x - t2.x;  Im[a2] = t0.y - t2.y;
        Re[a1] = t1.x + t3.y;  Im[a1] = t1.y - t3.x;
        Re[a3] = t1.x - t3.y;  Im[a3] = t1.y + t3.x;
      }
      __syncthreads();
    }
  }

  float2 pv[16];
#pragma unroll
  for (int i = 0; i < 16; ++i) {
    const int n = tid + 256 * i;
    const int u = n >> 6, vv = n & 63;
    const int u2 = (64 - u) & 63, v2 = (64 - vv) & 63;
    const int az = SWA(u, vv), am = SWA(u2, v2);
    const float zr = Re[az], zi = Im[az];
    const float mr = Re[am], mi = Im[am];
    const float dre = zr * zr - zi * zi - mr * mr + mi * mi;
    const float dim = 2.f * (zr * zi + mr * mi);
    pv[i] = make_float2(0.25f * dim, -0.25f * dre);
  }
  __syncthreads();
#pragma unroll
  for (int i = 0; i < 16; ++i) {
    const int n = tid + 256 * i;
    const int az = SWA(n >> 6, n & 63);
    Re[az] = pv[i].x;
    Im[az] = pv[i].y;
  }
  __syncthreads();

  for (int pass = 0; pass < 2; ++pass) {
    for (int s = 2; s >= 0; --s) {
      const int h  = 1 << (2 * s);
      const int us = 16 >> (2 * s);
#pragma unroll
      for (int q = 0; q < 4; ++q) {
        const int k = kb + 4 * q;
        const int j = k & (h - 1);
        const int g = k >> (2 * s);
        const int bse = g * 4 * h + j;
        const int p0 = bse, p1 = bse + h, p2 = bse + 2 * h, p3 = bse + 3 * h;
        const int a0 = pass ? SWA(lane, p0) : SWA(p0, lane);
        const int a1 = pass ? SWA(lane, p1) : SWA(p1, lane);
        const int a2 = pass ? SWA(lane, p2) : SWA(p2, lane);
        const int a3 = pass ? SWA(lane, p3) : SWA(p3, lane);
        const float2 x0 = make_float2(Re[a0], Im[a0]);
        const float2 x1 = make_float2(Re[a1], Im[a1]);
        const float2 x2 = make_float2(Re[a2], Im[a2]);
        const float2 x3 = make_float2(Re[a3], Im[a3]);
        const float2 t0 = make_float2(x0.x + x2.x, x0.y + x2.y);
        const float2 t1 = make_float2(x0.x - x2.x, x0.y - x2.y);
        const float2 t2 = make_float2(x1.x + x3.x, x1.y + x3.y);
        const float2 t3 = make_float2(x1.x - x3.x, x1.y - x3.y);
        const float2 y0 = make_float2(t0.x + t2.x, t0.y + t2.y);
        float2 y2 = make_float2(t0.x - t2.x, t0.y - t2.y);
        float2 y1 = make_float2(t1.x - t3.y, t1.y + t3.x);
        float2 y3 = make_float2(t1.x + t3.y, t1.y - t3.x);
        const int e = j * us;
        y1 = cmulc(y1, twt[e & 63]);
        y2 = cmulc(y2, twt[(2 * e) & 63]);
        y3 = cmulc(y3, twt[(3 * e) & 63]);
        Re[a0] = y0.x;  Im[a0] = y0.y;
        Re[a1] = y1.x;  Im[a1] = y1.y;
        Re[a2] = y2.x;  Im[a2] = y2.y;
        Re[a3] = y3.x;  Im[a3] = y3.y;
      }
      __syncthreads();
    }
  }

  float4* S4 = (float4*)(Sg + base);
#pragma unroll
  for (int i = 0; i < 4; ++i) {
    const int v = tid + 256 * i;
    const int y = v >> 4, w = v & 15;
    const int Rr = REV6(y);
    const int cb = ((w & 3) << 2) | (w >> 2);
    float4 o;
    o.x = Re[SWA(Rr, cb)]      * (1.f / 4096.f);
    o.y = Re[SWA(Rr, cb + 16)] * (1.f / 4096.f);
    o.z = Re[SWA(Rr, cb + 32)] * (1.f / 4096.f);
    o.w = Re[SWA(Rr, cb + 48)] * (1.f / 4096.f);
    S4[v] = o;
  }
}

// ---------------------------------------------------------------------------
// Fused split-K reduce + row softmax
// ---------------------------------------------------------------------------
__global__ __launch_bounds__(256)
void softmax_kernel(const float* __restrict__ Lp, float* __restrict__ L,
                    const float* __restrict__ alpha)
{
  __shared__ float red[256];
  const int row = blockIdx.x, tid = threadIdx.x;
  const int b = row >> 8, c = row & 255;
  const float sc = 4096.f / alpha[0];
  float acc = 0.f;
#pragma unroll
  for (int s = 0; s < SPLITK; ++s)
    acc += Lp[((long)(b * SPLITK + s) * 65536) + (long)c * 256 + tid];
  const float v = fabsf(acc) * sc;
  red[tid] = v; __syncthreads();
  for (int o = 128; o > 0; o >>= 1) {
    if (tid < o) red[tid] = fmaxf(red[tid], red[tid + o]);
    __syncthreads();
  }
  const float mx = red[0];
  __syncthreads();
  const float e = expf(v - mx);
  red[tid] = e; __syncthreads();
  for (int o = 128; o > 0; o >>= 1) {
    if (tid < o) red[tid] += red[tid + o];
    __syncthreads();
  }
  L[(long)row * 256 + tid] = e / red[0];
}

// ---------------------------------------------------------------------------
extern "C" void kernel_launch(void* const* d_in, const int* in_sizes, int n_in,
                              void* d_out, int out_size, void* d_ws, size_t ws_size,
                              hipStream_t stream)
{
  const float* x1       = (const float*)d_in[0];
  const float* x2       = (const float*)d_in[1];
  const float* conv_r_w = (const float*)d_in[2];
  const float* conv_r_b = (const float*)d_in[3];
  const float* conv_n_w = (const float*)d_in[4];
  const float* conv_n_b = (const float*)d_in[5];
  const float* mlp_w1   = (const float*)d_in[6];
  const float* mlp_w2   = (const float*)d_in[7];
  const float* pq_w     = (const float*)d_in[8];
  const float* pq_b     = (const float*)d_in[9];
  const float* dq_w     = (const float*)d_in[10];
  const float* dq_b     = (const float*)d_in[11];
  const float* pk_w     = (const float*)d_in[12];
  const float* pk_b     = (const float*)d_in[13];
  const float* dk_w     = (const float*)d_in[14];
  const float* dk_b     = (const float*)d_in[15];
  const float* pv_w     = (const float*)d_in[16];
  const float* pv_b     = (const float*)d_in[17];
  const float* dv_w     = (const float*)d_in[18];
  const float* dv_b     = (const float*)d_in[19];
  const float* out_w    = (const float*)d_in[20];
  const float* out_b    = (const float*)d_in[21];
  const float* alpha    = (const float*)d_in[22];
  const float* lambd    = (const float*)d_in[23];
  const float* beta     = (const float*)d_in[24];

  float* s = (float*)d_ws;
  float* S0 = s;             // FR  -> Q
  float* S1 = s + SLOT;      // FN  -> K
  float* S2 = s + 2 * SLOT;  // Fw  -> mix (in-place)
  float* S3 = s + 3 * SLOT;  // Pq  -> Krev
  float* S4 = s + 4 * SLOT;  // Pk  -> V
  float* S5 = s + 5 * SLOT;  // Pv  -> S
  float* Lp     = s + 6 * SLOT;                       // [8][SPLITK][256][256]
  float* Lb     = Lp + (long)8 * SPLITK * 256 * 256;  // [8][256][256]
  float* pooled = Lb + (long)8 * 256 * 256;
  float* attn2  = pooled + 2048;

  const size_t needed =
      (size_t)(6 * SLOT + (long)8 * SPLITK * 65536 + 8L * 65536 + 2048 + 4096)
      * sizeof(float);
  if (ws_size < needed) return;

  const long ST  = (long)CH * HW;   // 1048576
  const long ST2 = (long)128 * HW;
  const long STL = (long)256 * 256;

  const dim3 gBig(32, 2, 8);   // 4096/128 n-tiles, 256/128 m-tiles, 8 batches

  // FR = conv_r(x1), FN = conv_n(x2)
  gemm_mfma<0><<<gBig, 256, 0, stream>>>(conv_r_w, x1, S0, conv_r_b,
      256, 0L, ST, ST, nullptr, nullptr, nullptr, nullptr, nullptr);
  gemm_mfma<0><<<gBig, 256, 0, stream>>>(conv_n_w, x2, S1, conv_n_b,
      128, 0L, ST2, ST, nullptr, nullptr, nullptr, nullptr, nullptr);

  pool_kernel<<<2048, 256, 0, stream>>>(S0, S1, pooled);
  attn2_kernel<<<8, 256, 0, stream>>>(pooled, mlp_w1, mlp_w2, attn2);
  fw_kernel<<<dim3(4, 256, 8), 256, 0, stream>>>(S0, S1, attn2, S2);

  // Pq/Pk/Pv = 1x1 convs of Fw
  gemm_mfma<0><<<gBig, 256, 0, stream>>>(pq_w, S2, S3, pq_b,
      256, 0L, ST, ST, nullptr, nullptr, nullptr, nullptr, nullptr);
  gemm_mfma<0><<<gBig, 256, 0, stream>>>(pk_w, S2, S4, pk_b,
      256, 0L, ST, ST, nullptr, nullptr, nullptr, nullptr, nullptr);
  gemm_mfma<0><<<gBig, 256, 0, stream>>>(pv_w, S2, S5, pv_b,
      256, 0L, ST, ST, nullptr, nullptr, nullptr, nullptr, nullptr);

  // depthwise 3x3
  dw_kernel<<<2048, 256, 0, stream>>>(S3, dq_w, dq_b, S0, nullptr);  // Q  -> S0
  dw_kernel<<<2048, 256, 0, stream>>>(S4, dk_w, dk_b, S1, S3);       // K  -> S1, Krev -> S3
  dw_kernel<<<2048, 256, 0, stream>>>(S5, dv_w, dv_b, S4, nullptr);  // V  -> S4

  // S = circconv2(Q, K) per channel
  sconv_kernel<<<2048, 256, 0, stream>>>(S0, S1, S5);                // S -> S5

  // attn logits: split-K partials (vector kernel), then fused reduce+softmax
  gemm_kernel<true, 3><<<dim3(2, 2, 8 * SPLITK), 256, 0, stream>>>(
      S0, S3, Lp, nullptr, 256, 256, 4096, SPLITK, ST, ST, STL);
  softmax_kernel<<<2048, 256, 0, stream>>>(Lp, Lb, alpha);

  // cfr = attn_w @ S, fused mix epilogue (in-place into S2)
  gemm_mfma<2><<<gBig, 256, 0, stream>>>(Lb, S5, S2, nullptr,
      256, STL, ST, ST, S0, S4, S2, lambd, beta);

  // final 1x1 conv -> d_out
  gemm_mfma<0><<<gBig, 256, 0, stream>>>(out_w, S2, (float*)d_out, out_b,
      256, 0L, ST, ST, nullptr, nullptr, nullptr, nullptr, nullptr);
}

// Round 6
// 459.714 us; speedup vs baseline: 2.3121x; 1.1248x over previous
//
#include <hip/hip_runtime.h>
#include <math.h>

#ifndef M_PI
#define M_PI 3.14159265358979323846
#endif

typedef unsigned int u32;

// Problem constants
constexpr int  NB   = 8;
constexpr int  CH   = 256;
constexpr long HW   = 4096;                 // 64*64
constexpr long SLOT = (long)NB * CH * HW;   // elems per [8,256,64,64] tensor
constexpr int  SPLITK = 8;                  // logits GEMM split factor
constexpr long ST   = (long)CH * HW;        // 1048576

// ===========================================================================
// Packed split-bf16 format: u32 = bits(bf16_rne_hi(x)) | bits(bf16_trunc(lo))>>16
//   hi in top 16 bits, lo in low 16 bits; reconstruction error ~2^-17 relative.
// ===========================================================================
__device__ __forceinline__ float rne_hi(float x) {
  unsigned u = __float_as_uint(x);
  unsigned r = (u + 0x7FFFu + ((u >> 16) & 1u)) & 0xFFFF0000u;
  return __uint_as_float(r);
}
__device__ __forceinline__ u32 packf(float x) {
  const float h = rne_hi(x);
  const float l = x - h;
  return (__float_as_uint(h) & 0xFFFF0000u) | (__float_as_uint(l) >> 16);
}
__device__ __forceinline__ float unpackf(u32 u) {
  return __uint_as_float(u & 0xFFFF0000u) + __uint_as_float(u << 16);
}
__device__ __forceinline__ unsigned bfpair(float x, float y) {
  return (__float_as_uint(x) >> 16) | (__float_as_uint(y) & 0xFFFF0000u);
}

typedef short bf16x8 __attribute__((ext_vector_type(8)));
typedef float f32x4  __attribute__((ext_vector_type(4)));

// ===========================================================================
// cvt: fp32 -> packed u32 plane (weights / small tensors); n4 = n/4
// ===========================================================================
__global__ __launch_bounds__(256)
void cvt_kernel(const float* __restrict__ src, u32* __restrict__ dst, int n4)
{
  const int i = blockIdx.x * 256 + threadIdx.x;
  if (i < n4) {
    const float4 v = ((const float4*)src)[i];
    uint4 o;
    o.x = packf(v.x); o.y = packf(v.y); o.z = packf(v.z); o.w = packf(v.w);
    ((uint4*)dst)[i] = o;
  }
}

// ===========================================================================
// MFMA split-bf16 GEMM: C[b](256 x 4096) = A[b](256 x K) * B[b](K x 4096)
// A always packed-u32 [M][K]. B: BPACKED ? packed-u32 [K][N] : fp32 [K][N].
// 3-product emulation: C ~= Ah*Bh + Ah*Bl + Al*Bh.
// Tile 128x128, BK=32, 4 waves 2x2, wave = 4x4 of mfma 16x16x32.
// EPI 0: fp32 +bias store (final). EPI 1: packed +bias store.
// EPI 2: mix = beta*(cfr*(Q-lam*V)+V)+(1-beta)*Fw -> packed store.
// ===========================================================================
template<bool BPACKED, int EPI>
__global__ __launch_bounds__(256)
void gemm_mfma(const u32* __restrict__ A, const void* __restrict__ Bv,
               void* __restrict__ Cv, const float* __restrict__ bias,
               int K, long aStride, long bStride, long cStride,
               const u32* __restrict__ qb, const u32* __restrict__ vb,
               const u32* __restrict__ fwb,
               const float* __restrict__ lambd, const float* __restrict__ beta)
{
  constexpr int N = 4096;
  __shared__ __align__(16) unsigned short sAh[128 * 48];
  __shared__ __align__(16) unsigned short sAl[128 * 48];
  __shared__ __align__(16) unsigned short sBh[128 * 48];
  __shared__ __align__(16) unsigned short sBl[128 * 48];

  const int tid = threadIdx.x;
  const int b   = blockIdx.z;
  const int m0  = blockIdx.y * 128;
  const int n0  = blockIdx.x * 128;
  const u32* Ab = A + (long)b * aStride;

  const int ar = tid >> 1;
  const int ak = (tid & 1) * 16;
  const int aBase = ar * 48 + ak;
  const int bn = tid & 127;
  const int bk = (tid >> 7) * 16;
  const int bBase = bn * 48 + bk;

  const int wv = tid >> 6, lane = tid & 63;
  const int wy = wv >> 1, wx = wv & 1;
  const int quad = lane >> 4, l15 = lane & 15;

  f32x4 acc[4][4];
#pragma unroll
  for (int i = 0; i < 4; ++i)
#pragma unroll
    for (int j = 0; j < 4; ++j) acc[i][j] = (f32x4){0.f, 0.f, 0.f, 0.f};

  u32   ra[16];
  u32   rbu[16];
  float rbf[16];
  {
    const u32* ap = Ab + (long)(m0 + ar) * K + ak;
#pragma unroll
    for (int i = 0; i < 4; ++i) {
      const uint4 t = *(const uint4*)(ap + i * 4);
      ra[4*i] = t.x; ra[4*i+1] = t.y; ra[4*i+2] = t.z; ra[4*i+3] = t.w;
    }
    if (BPACKED) {
      const u32* bp = (const u32*)Bv + (long)b * bStride + (long)bk * N + n0 + bn;
#pragma unroll
      for (int i = 0; i < 16; ++i) rbu[i] = bp[(long)i * N];
    } else {
      const float* bp = (const float*)Bv + (long)b * bStride + (long)bk * N + n0 + bn;
#pragma unroll
      for (int i = 0; i < 16; ++i) rbf[i] = bp[(long)i * N];
    }
  }

  for (int kt = 0; kt < K; kt += 32) {
    // commit A (packed split: 4 ops / 2 elems)
    {
      u32 hi[8], lo[8];
#pragma unroll
      for (int e = 0; e < 8; ++e) {
        const u32 u0 = ra[2*e], u1 = ra[2*e+1];
        hi[e] = (u0 >> 16) | (u1 & 0xFFFF0000u);
        lo[e] = (u0 & 0xFFFFu) | (u1 << 16);
      }
      *(uint4*)&sAh[aBase]     = make_uint4(hi[0], hi[1], hi[2], hi[3]);
      *(uint4*)&sAh[aBase + 8] = make_uint4(hi[4], hi[5], hi[6], hi[7]);
      *(uint4*)&sAl[aBase]     = make_uint4(lo[0], lo[1], lo[2], lo[3]);
      *(uint4*)&sAl[aBase + 8] = make_uint4(lo[4], lo[5], lo[6], lo[7]);
    }
    // commit B
    if (BPACKED) {
      u32 hi[8], lo[8];
#pragma unroll
      for (int e = 0; e < 8; ++e) {
        const u32 u0 = rbu[2*e], u1 = rbu[2*e+1];
        hi[e] = (u0 >> 16) | (u1 & 0xFFFF0000u);
        lo[e] = (u0 & 0xFFFFu) | (u1 << 16);
      }
      *(uint4*)&sBh[bBase]     = make_uint4(hi[0], hi[1], hi[2], hi[3]);
      *(uint4*)&sBh[bBase + 8] = make_uint4(hi[4], hi[5], hi[6], hi[7]);
      *(uint4*)&sBl[bBase]     = make_uint4(lo[0], lo[1], lo[2], lo[3]);
      *(uint4*)&sBl[bBase + 8] = make_uint4(lo[4], lo[5], lo[6], lo[7]);
    } else {
      float h[16], l[16];
#pragma unroll
      for (int e = 0; e < 16; ++e) { h[e] = rne_hi(rbf[e]); l[e] = rbf[e] - h[e]; }
      *(uint4*)&sBh[bBase]     = make_uint4(bfpair(h[0],h[1]), bfpair(h[2],h[3]),
                                            bfpair(h[4],h[5]), bfpair(h[6],h[7]));
      *(uint4*)&sBh[bBase + 8] = make_uint4(bfpair(h[8],h[9]), bfpair(h[10],h[11]),
                                            bfpair(h[12],h[13]), bfpair(h[14],h[15]));
      *(uint4*)&sBl[bBase]     = make_uint4(bfpair(l[0],l[1]), bfpair(l[2],l[3]),
                                            bfpair(l[4],l[5]), bfpair(l[6],l[7]));
      *(uint4*)&sBl[bBase + 8] = make_uint4(bfpair(l[8],l[9]), bfpair(l[10],l[11]),
                                            bfpair(l[12],l[13]), bfpair(l[14],l[15]));
    }
    __syncthreads();

    // prefetch next tile
    if (kt + 32 < K) {
      const u32* ap = Ab + (long)(m0 + ar) * K + kt + 32 + ak;
#pragma unroll
      for (int i = 0; i < 4; ++i) {
        const uint4 t = *(const uint4*)(ap + i * 4);
        ra[4*i] = t.x; ra[4*i+1] = t.y; ra[4*i+2] = t.z; ra[4*i+3] = t.w;
      }
      if (BPACKED) {
        const u32* bp = (const u32*)Bv + (long)b * bStride + (long)(kt + 32 + bk) * N + n0 + bn;
#pragma unroll
        for (int i = 0; i < 16; ++i) rbu[i] = bp[(long)i * N];
      } else {
        const float* bp = (const float*)Bv + (long)b * bStride + (long)(kt + 32 + bk) * N + n0 + bn;
#pragma unroll
        for (int i = 0; i < 16; ++i) rbf[i] = bp[(long)i * N];
      }
    }

    // fragments + 48 MFMA
    bf16x8 ah[4], al[4];
#pragma unroll
    for (int i = 0; i < 4; ++i) {
      const int idx = (wy * 64 + i * 16 + l15) * 48 + quad * 8;
      ah[i] = *(const bf16x8*)&sAh[idx];
      al[i] = *(const bf16x8*)&sAl[idx];
    }
#pragma unroll
    for (int j = 0; j < 4; ++j) {
      const int idx = (wx * 64 + j * 16 + l15) * 48 + quad * 8;
      const bf16x8 bh = *(const bf16x8*)&sBh[idx];
      const bf16x8 bl = *(const bf16x8*)&sBl[idx];
#pragma unroll
      for (int i = 0; i < 4; ++i) {
        acc[i][j] = __builtin_amdgcn_mfma_f32_16x16x32_bf16(ah[i], bh, acc[i][j], 0, 0, 0);
        acc[i][j] = __builtin_amdgcn_mfma_f32_16x16x32_bf16(ah[i], bl, acc[i][j], 0, 0, 0);
        acc[i][j] = __builtin_amdgcn_mfma_f32_16x16x32_bf16(al[i], bh, acc[i][j], 0, 0, 0);
      }
    }
    __syncthreads();
  }

  // epilogue
  if (EPI == 0) {
    float* Cb = (float*)Cv + (long)b * cStride;
#pragma unroll
    for (int i = 0; i < 4; ++i)
#pragma unroll
      for (int r = 0; r < 4; ++r) {
        const int row = m0 + wy * 64 + i * 16 + quad * 4 + r;
        const float bb = bias ? bias[row] : 0.f;
#pragma unroll
        for (int j = 0; j < 4; ++j) {
          const int col = n0 + wx * 64 + j * 16 + l15;
          Cb[(long)row * N + col] = acc[i][j][r] + bb;
        }
      }
  } else if (EPI == 1) {
    u32* Cb = (u32*)Cv + (long)b * cStride;
#pragma unroll
    for (int i = 0; i < 4; ++i)
#pragma unroll
      for (int r = 0; r < 4; ++r) {
        const int row = m0 + wy * 64 + i * 16 + quad * 4 + r;
        const float bb = bias ? bias[row] : 0.f;
#pragma unroll
        for (int j = 0; j < 4; ++j) {
          const int col = n0 + wx * 64 + j * 16 + l15;
          Cb[(long)row * N + col] = packf(acc[i][j][r] + bb);
        }
      }
  } else {
    u32* Cb = (u32*)Cv + (long)b * cStride;
    const float lam = lambd[0], bet = beta[0];
#pragma unroll
    for (int i = 0; i < 4; ++i)
#pragma unroll
      for (int r = 0; r < 4; ++r) {
        const int row = m0 + wy * 64 + i * 16 + quad * 4 + r;
#pragma unroll
        for (int j = 0; j < 4; ++j) {
          const int col = n0 + wx * 64 + j * 16 + l15;
          const long off = (long)row * N + col;
          const long gi  = (long)b * cStride + off;
          const float q = unpackf(qb[gi]);
          const float v = unpackf(vb[gi]);
          const float f = unpackf(fwb[gi]);
          Cb[off] = packf(bet * (acc[i][j][r] * (q - lam * v) + v) + (1.f - bet) * f);
        }
      }
  }
}

// ===========================================================================
// MFMA logits GEMM: Lp[b,s](256x256) = Q[b](256x4096) . Krev[b]^T over k-span s
// Both operands packed-u32, K-contiguous. Tile 128x128, split-K=8, BK=32.
// ===========================================================================
__global__ __launch_bounds__(256)
void gemm_logits(const u32* __restrict__ Q, const u32* __restrict__ Kr,
                 float* __restrict__ Lp)
{
  __shared__ __align__(16) unsigned short sAh[128 * 48];
  __shared__ __align__(16) unsigned short sAl[128 * 48];
  __shared__ __align__(16) unsigned short sBh[128 * 48];
  __shared__ __align__(16) unsigned short sBl[128 * 48];

  const int tid = threadIdx.x;
  const int bz  = blockIdx.z;            // b*8 + s
  const int b   = bz >> 3, sp = bz & 7;
  const int m0  = blockIdx.y * 128;
  const int n0  = blockIdx.x * 128;
  const long k0b = (long)sp * 512;

  const int ar = tid >> 1;
  const int ak = (tid & 1) * 16;
  const int aBase = ar * 48 + ak;

  const int wv = tid >> 6, lane = tid & 63;
  const int wy = wv >> 1, wx = wv & 1;
  const int quad = lane >> 4, l15 = lane & 15;

  f32x4 acc[4][4];
#pragma unroll
  for (int i = 0; i < 4; ++i)
#pragma unroll
    for (int j = 0; j < 4; ++j) acc[i][j] = (f32x4){0.f, 0.f, 0.f, 0.f};

  const u32* Abase = Q  + (long)b * ST + (long)(m0 + ar) * 4096 + k0b + ak;
  const u32* Bbase = Kr + (long)b * ST + (long)(n0 + ar) * 4096 + k0b + ak;

  u32 ra[16], rb[16];
#pragma unroll
  for (int i = 0; i < 4; ++i) {
    uint4 t = *(const uint4*)(Abase + i * 4);
    ra[4*i] = t.x; ra[4*i+1] = t.y; ra[4*i+2] = t.z; ra[4*i+3] = t.w;
    t = *(const uint4*)(Bbase + i * 4);
    rb[4*i] = t.x; rb[4*i+1] = t.y; rb[4*i+2] = t.z; rb[4*i+3] = t.w;
  }

  for (int kt = 0; kt < 512; kt += 32) {
    {
      u32 hi[8], lo[8];
#pragma unroll
      for (int e = 0; e < 8; ++e) {
        const u32 u0 = ra[2*e], u1 = ra[2*e+1];
        hi[e] = (u0 >> 16) | (u1 & 0xFFFF0000u);
        lo[e] = (u0 & 0xFFFFu) | (u1 << 16);
      }
      *(uint4*)&sAh[aBase]     = make_uint4(hi[0], hi[1], hi[2], hi[3]);
      *(uint4*)&sAh[aBase + 8] = make_uint4(hi[4], hi[5], hi[6], hi[7]);
      *(uint4*)&sAl[aBase]     = make_uint4(lo[0], lo[1], lo[2], lo[3]);
      *(uint4*)&sAl[aBase + 8] = make_uint4(lo[4], lo[5], lo[6], lo[7]);
#pragma unroll
      for (int e = 0; e < 8; ++e) {
        const u32 u0 = rb[2*e], u1 = rb[2*e+1];
        hi[e] = (u0 >> 16) | (u1 & 0xFFFF0000u);
        lo[e] = (u0 & 0xFFFFu) | (u1 << 16);
      }
      *(uint4*)&sBh[aBase]     = make_uint4(hi[0], hi[1], hi[2], hi[3]);
      *(uint4*)&sBh[aBase + 8] = make_uint4(hi[4], hi[5], hi[6], hi[7]);
      *(uint4*)&sBl[aBase]     = make_uint4(lo[0], lo[1], lo[2], lo[3]);
      *(uint4*)&sBl[aBase + 8] = make_uint4(lo[4], lo[5], lo[6], lo[7]);
    }
    __syncthreads();

    if (kt + 32 < 512) {
#pragma unroll
      for (int i = 0; i < 4; ++i) {
        uint4 t = *(const uint4*)(Abase + kt + 32 + i * 4);
        ra[4*i] = t.x; ra[4*i+1] = t.y; ra[4*i+2] = t.z; ra[4*i+3] = t.w;
        t = *(const uint4*)(Bbase + kt + 32 + i * 4);
        rb[4*i] = t.x; rb[4*i+1] = t.y; rb[4*i+2] = t.z; rb[4*i+3] = t.w;
      }
    }

    bf16x8 ah[4], al[4];
#pragma unroll
    for (int i = 0; i < 4; ++i) {
      const int idx = (wy * 64 + i * 16 + l15) * 48 + quad * 8;
      ah[i] = *(const bf16x8*)&sAh[idx];
      al[i] = *(const bf16x8*)&sAl[idx];
    }
#pragma unroll
    for (int j = 0; j < 4; ++j) {
      const int idx = (wx * 64 + j * 16 + l15) * 48 + quad * 8;
      const bf16x8 bh = *(const bf16x8*)&sBh[idx];
      const bf16x8 bl = *(const bf16x8*)&sBl[idx];
#pragma unroll
      for (int i = 0; i < 4; ++i) {
        acc[i][j] = __builtin_amdgcn_mfma_f32_16x16x32_bf16(ah[i], bh, acc[i][j], 0, 0, 0);
        acc[i][j] = __builtin_amdgcn_mfma_f32_16x16x32_bf16(ah[i], bl, acc[i][j], 0, 0, 0);
        acc[i][j] = __builtin_amdgcn_mfma_f32_16x16x32_bf16(al[i], bh, acc[i][j], 0, 0, 0);
      }
    }
    __syncthreads();
  }

  float* Lb = Lp + (long)bz * 65536;
#pragma unroll
  for (int i = 0; i < 4; ++i)
#pragma unroll
    for (int r = 0; r < 4; ++r) {
      const int row = m0 + wy * 64 + i * 16 + quad * 4 + r;
#pragma unroll
      for (int j = 0; j < 4; ++j) {
        const int col = n0 + wx * 64 + j * 16 + l15;
        Lb[(long)row * 256 + col] = acc[i][j][r];
      }
    }
}

// ---------------------------------------------------------------------------
// pooled[b,c] = mean over HW of (FR + FN)   (packed inputs)
// ---------------------------------------------------------------------------
__global__ __launch_bounds__(256)
void pool_kernel(const u32* __restrict__ FR, const u32* __restrict__ FN,
                 float* __restrict__ pooled)
{
  __shared__ float red[256];
  const int bc = blockIdx.x, tid = threadIdx.x;
  const uint4* a = (const uint4*)(FR + (long)bc * HW);
  const uint4* b = (const uint4*)(FN + (long)bc * HW);
  float s = 0.f;
  for (int v = tid; v < 1024; v += 256) {
    const uint4 x = a[v];
    s += unpackf(x.x) + unpackf(x.y) + unpackf(x.z) + unpackf(x.w);
    const uint4 y = b[v];
    s += unpackf(y.x) + unpackf(y.y) + unpackf(y.z) + unpackf(y.w);
  }
  red[tid] = s; __syncthreads();
  for (int o = 128; o > 0; o >>= 1) {
    if (tid < o) red[tid] += red[tid + o];
    __syncthreads();
  }
  if (tid == 0) pooled[bc] = red[0] * (1.f / 4096.f);
}

// ---------------------------------------------------------------------------
// MLP (relu) + 2-way softmax -> attn2 [8,2,256]  (fp32 throughout)
// ---------------------------------------------------------------------------
__global__ __launch_bounds__(256)
void attn2_kernel(const float* __restrict__ pooled, const float* __restrict__ w1,
                  const float* __restrict__ w2, float* __restrict__ attn2)
{
  __shared__ float ps[256];
  __shared__ float hs[32];
  const int b = blockIdx.x, tid = threadIdx.x;
  ps[tid] = pooled[b * 256 + tid];
  __syncthreads();
  if (tid < 32) {
    float a = 0.f;
    for (int c = 0; c < 256; ++c) a += ps[c] * w1[tid * 256 + c];
    hs[tid] = fmaxf(a, 0.f);
  }
  __syncthreads();
  float a0 = 0.f, a1 = 0.f;
  for (int d = 0; d < 32; ++d) {
    const float h = hs[d];
    a0 += h * w2[tid * 32 + d];
    a1 += h * w2[(256 + tid) * 32 + d];
  }
  const float m  = fmaxf(a0, a1);
  const float e0 = expf(a0 - m), e1 = expf(a1 - m);
  const float inv = 1.f / (e0 + e1);
  attn2[b * 512 + tid]       = e0 * inv;
  attn2[b * 512 + 256 + tid] = e1 * inv;
}

// ---------------------------------------------------------------------------
// Fw = a0*FR + a1*FN   (packed in, packed out)
// ---------------------------------------------------------------------------
__global__ __launch_bounds__(256)
void fw_kernel(const u32* __restrict__ FR, const u32* __restrict__ FN,
               const float* __restrict__ attn2, u32* __restrict__ FW)
{
  const int b = blockIdx.z, c = blockIdx.y;
  const float a0 = attn2[b * 512 + c];
  const float a1 = attn2[b * 512 + 256 + c];
  const long base4 = ((long)b * 256 + c) * 1024;
  const int i = blockIdx.x * 256 + threadIdx.x;
  const uint4 r = ((const uint4*)FR)[base4 + i];
  const uint4 n = ((const uint4*)FN)[base4 + i];
  uint4 o;
  o.x = packf(a0 * unpackf(r.x) + a1 * unpackf(n.x));
  o.y = packf(a0 * unpackf(r.y) + a1 * unpackf(n.y));
  o.z = packf(a0 * unpackf(r.z) + a1 * unpackf(n.z));
  o.w = packf(a0 * unpackf(r.w) + a1 * unpackf(n.w));
  ((uint4*)FW)[base4 + i] = o;
}

// ---------------------------------------------------------------------------
// Depthwise 3x3, SAME padding; packed in/out; optional index-reversed copy.
// ---------------------------------------------------------------------------
__global__ __launch_bounds__(256)
void dw_kernel(const u32* __restrict__ in, const float* __restrict__ w,
               const float* __restrict__ bias, u32* __restrict__ out,
               u32* __restrict__ out_rev)
{
  __shared__ float img[66][66];
  const int bc = blockIdx.x, tid = threadIdx.x;
  const int c = bc & 255;
  for (int v = tid; v < 66 * 66; v += 256) ((float*)img)[v] = 0.f;
  __syncthreads();
  const uint4* in4 = (const uint4*)(in + (long)bc * HW);
  for (int v = tid; v < 1024; v += 256) {
    const uint4 x = in4[v];
    const int r = v >> 4, c0 = ((v & 15) << 2) + 1;
    img[r + 1][c0 + 0] = unpackf(x.x);
    img[r + 1][c0 + 1] = unpackf(x.y);
    img[r + 1][c0 + 2] = unpackf(x.z);
    img[r + 1][c0 + 3] = unpackf(x.w);
  }
  float wr[9];
#pragma unroll
  for (int j = 0; j < 9; ++j) wr[j] = w[c * 9 + j];
  const float bb = bias[c];
  __syncthreads();
  for (int p = tid; p < 4096; p += 256) {
    const int y = p >> 6, x = p & 63;
    float s = bb;
#pragma unroll
    for (int ky = 0; ky < 3; ++ky)
#pragma unroll
      for (int kx = 0; kx < 3; ++kx)
        s = fmaf(wr[ky * 3 + kx], img[y + ky][x + kx], s);
    const u32 u = packf(s);
    out[(long)bc * HW + p] = u;
    if (out_rev)
      out_rev[(long)bc * HW + (((64 - y) & 63) << 6) + ((64 - x) & 63)] = u;
  }
}

// ---------------------------------------------------------------------------
// S[b,c] = circconv2(Q[b,c], K[b,c]) via ONE packed radix-4 FFT (packed I/O)
// ---------------------------------------------------------------------------
#define SWA(r, c) (((r) << 6) | ((c) ^ (r)))
#define REV6(x)   ((((x) & 3) << 4) | ((x) & 12) | ((x) >> 4))

__device__ __forceinline__ float2 cmul(float2 a, float2 w) {
  return make_float2(a.x * w.x - a.y * w.y, a.x * w.y + a.y * w.x);
}
__device__ __forceinline__ float2 cmulc(float2 a, float2 w) {
  return make_float2(a.x * w.x + a.y * w.y, a.y * w.x - a.x * w.y);
}

__global__ __launch_bounds__(256, 4)
void sconv_kernel(const u32* __restrict__ Qg, const u32* __restrict__ Kg,
                  u32* __restrict__ Sg)
{
  __shared__ float Re[4096];
  __shared__ float Im[4096];
  __shared__ float2 twt[64];
  const int tid = threadIdx.x;
  const long base = (long)blockIdx.x * 4096;
  if (tid < 64) {
    float sn, cs;
    __sincosf(-2.f * (float)M_PI * (float)tid * (1.f / 64.f), &sn, &cs);
    twt[tid] = make_float2(cs, sn);
  }
  const uint4* Q4 = (const uint4*)(Qg + base);
  const uint4* K4 = (const uint4*)(Kg + base);
#pragma unroll
  for (int i = 0; i < 4; ++i) {
    const int v = tid + 256 * i;
    const uint4 q = Q4[v], k = K4[v];
    const int r = v >> 4, w = v & 15;
    const int R  = REV6(r);
    const int cb = ((w & 3) << 2) | (w >> 2);
    Re[SWA(R, cb)]      = unpackf(q.x);  Im[SWA(R, cb)]      = unpackf(k.x);
    Re[SWA(R, cb + 16)] = unpackf(q.y);  Im[SWA(R, cb + 16)] = unpackf(k.y);
    Re[SWA(R, cb + 32)] = unpackf(q.z);  Im[SWA(R, cb + 32)] = unpackf(k.z);
    Re[SWA(R, cb + 48)] = unpackf(q.w);  Im[SWA(R, cb + 48)] = unpackf(k.w);
  }
  __syncthreads();

  const int lane = tid & 63;
  const int kb   = tid >> 6;

  for (int pass = 0; pass < 2; ++pass) {
    for (int s = 0; s < 3; ++s) {
      const int h  = 1 << (2 * s);
      const int us = 16 >> (2 * s);
#pragma unroll
      for (int q = 0; q < 4; ++q) {
        const int k = kb + 4 * q;
        const int j = k & (h - 1);
        const int g = k >> (2 * s);
        const int bse = g * 4 * h + j;
        const int p0 = bse, p1 = bse + h, p2 = bse + 2 * h, p3 = bse + 3 * h;
        const int a0 = pass ? SWA(p0, lane) : SWA(lane, p0);
        const int a1 = pass ? SWA(p1, lane) : SWA(lane, p1);
        const int a2 = pass ? SWA(p2, lane) : SWA(lane, p2);
        const int a3 = pass ? SWA(p3, lane) : SWA(lane, p3);
        float2 x0 = make_float2(Re[a0], Im[a0]);
        float2 x1 = make_float2(Re[a1], Im[a1]);
        float2 x2 = make_float2(Re[a2], Im[a2]);
        float2 x3 = make_float2(Re[a3], Im[a3]);
        const int e = j * us;
        x1 = cmul(x1, twt[e & 63]);
        x2 = cmul(x2, twt[(2 * e) & 63]);
        x3 = cmul(x3, twt[(3 * e) & 63]);
        const float2 t0 = make_float2(x0.x + x2.x, x0.y + x2.y);
        const float2 t1 = make_float2(x0.x - x2.x, x0.y - x2.y);
        const float2 t2 = make_float2(x1.x + x3.x, x1.y + x3.y);
        const float2 t3 = make_float2(x1.x - x3.x, x1.y - x3.y);
        Re[a0] = t0.x + t2.x;  Im[a0] = t0.y + t2.y;
        Re[a2] = t0.x - t2.x;  Im[a2] = t0.y - t2.y;
        Re[a1] = t1.x + t3.y;  Im[a1] = t1.y - t3.x;
        Re[a3] = t1.x - t3.y;  Im[a3] = t1.y + t3.x;
      }
      __syncthreads();
    }
  }

  float2 pv[16];
#pragma unroll
  for (int i = 0; i < 16; ++i) {
    const int n = tid + 256 * i;
    const int u = n >> 6, vv = n & 63;
    const int u2 = (64 - u) & 63, v2 = (64 - vv) & 63;
    const int az = SWA(u, vv), am = SWA(u2, v2);
    const float zr = Re[az], zi = Im[az];
    const float mr = Re[am], mi = Im[am];
    const float dre = zr * zr - zi * zi - mr * mr + mi * mi;
    const float dim = 2.f * (zr * zi + mr * mi);
    pv[i] = make_float2(0.25f * dim, -0.25f * dre);
  }
  __syncthreads();
#pragma unroll
  for (int i = 0; i < 16; ++i) {
    const int n = tid + 256 * i;
    const int az = SWA(n >> 6, n & 63);
    Re[az] = pv[i].x;
    Im[az] = pv[i].y;
  }
  __syncthreads();

  for (int pass = 0; pass < 2; ++pass) {
    for (int s = 2; s >= 0; --s) {
      const int h  = 1 << (2 * s);
      const int us = 16 >> (2 * s);
#pragma unroll
      for (int q = 0; q < 4; ++q) {
        const int k = kb + 4 * q;
        const int j = k & (h - 1);
        const int g = k >> (2 * s);
        const int bse = g * 4 * h + j;
        const int p0 = bse, p1 = bse + h, p2 = bse + 2 * h, p3 = bse + 3 * h;
        const int a0 = pass ? SWA(lane, p0) : SWA(p0, lane);
        const int a1 = pass ? SWA(lane, p1) : SWA(p1, lane);
        const int a2 = pass ? SWA(lane, p2) : SWA(p2, lane);
        const int a3 = pass ? SWA(lane, p3) : SWA(p3, lane);
        const float2 x0 = make_float2(Re[a0], Im[a0]);
        const float2 x1 = make_float2(Re[a1], Im[a1]);
        const float2 x2 = make_float2(Re[a2], Im[a2]);
        const float2 x3 = make_float2(Re[a3], Im[a3]);
        const float2 t0 = make_float2(x0.x + x2.x, x0.y + x2.y);
        const float2 t1 = make_float2(x0.x - x2.x, x0.y - x2.y);
        const float2 t2 = make_float2(x1.x + x3.x, x1.y + x3.y);
        const float2 t3 = make_float2(x1.x - x3.x, x1.y - x3.y);
        const float2 y0 = make_float2(t0.x + t2.x, t0.y + t2.y);
        float2 y2 = make_float2(t0.x - t2.x, t0.y - t2.y);
        float2 y1 = make_float2(t1.x - t3.y, t1.y + t3.x);
        float2 y3 = make_float2(t1.x + t3.y, t1.y - t3.x);
        const int e = j * us;
        y1 = cmulc(y1, twt[e & 63]);
        y2 = cmulc(y2, twt[(2 * e) & 63]);
        y3 = cmulc(y3, twt[(3 * e) & 63]);
        Re[a0] = y0.x;  Im[a0] = y0.y;
        Re[a1] = y1.x;  Im[a1] = y1.y;
        Re[a2] = y2.x;  Im[a2] = y2.y;
        Re[a3] = y3.x;  Im[a3] = y3.y;
      }
      __syncthreads();
    }
  }

  uint4* S4 = (uint4*)(Sg + base);
#pragma unroll
  for (int i = 0; i < 4; ++i) {
    const int v = tid + 256 * i;
    const int y = v >> 4, w = v & 15;
    const int Rr = REV6(y);
    const int cb = ((w & 3) << 2) | (w >> 2);
    uint4 o;
    o.x = packf(Re[SWA(Rr, cb)]      * (1.f / 4096.f));
    o.y = packf(Re[SWA(Rr, cb + 16)] * (1.f / 4096.f));
    o.z = packf(Re[SWA(Rr, cb + 32)] * (1.f / 4096.f));
    o.w = packf(Re[SWA(Rr, cb + 48)] * (1.f / 4096.f));
    S4[v] = o;
  }
}

// ---------------------------------------------------------------------------
// Fused split-K reduce + row softmax; writes PACKED attn weights.
// ---------------------------------------------------------------------------
__global__ __launch_bounds__(256)
void softmax_kernel(const float* __restrict__ Lp, u32* __restrict__ L,
                    const float* __restrict__ alpha)
{
  __shared__ float red[256];
  const int row = blockIdx.x, tid = threadIdx.x;
  const int b = row >> 8, c = row & 255;
  const float sc = 4096.f / alpha[0];
  float acc = 0.f;
#pragma unroll
  for (int s = 0; s < SPLITK; ++s)
    acc += Lp[((long)(b * SPLITK + s) * 65536) + (long)c * 256 + tid];
  const float v = fabsf(acc) * sc;
  red[tid] = v; __syncthreads();
  for (int o = 128; o > 0; o >>= 1) {
    if (tid < o) red[tid] = fmaxf(red[tid], red[tid + o]);
    __syncthreads();
  }
  const float mx = red[0];
  __syncthreads();
  const float e = expf(v - mx);
  red[tid] = e; __syncthreads();
  for (int o = 128; o > 0; o >>= 1) {
    if (tid < o) red[tid] += red[tid + o];
    __syncthreads();
  }
  L[(long)row * 256 + tid] = packf(e / red[0]);
}

// ---------------------------------------------------------------------------
extern "C" void kernel_launch(void* const* d_in, const int* in_sizes, int n_in,
                              void* d_out, int out_size, void* d_ws, size_t ws_size,
                              hipStream_t stream)
{
  const float* x1       = (const float*)d_in[0];
  const float* x2       = (const float*)d_in[1];
  const float* conv_r_w = (const float*)d_in[2];
  const float* conv_r_b = (const float*)d_in[3];
  const float* conv_n_w = (const float*)d_in[4];
  const float* conv_n_b = (const float*)d_in[5];
  const float* mlp_w1   = (const float*)d_in[6];
  const float* mlp_w2   = (const float*)d_in[7];
  const float* pq_w     = (const float*)d_in[8];
  const float* pq_b     = (const float*)d_in[9];
  const float* dq_w     = (const float*)d_in[10];
  const float* dq_b     = (const float*)d_in[11];
  const float* pk_w     = (const float*)d_in[12];
  const float* pk_b     = (const float*)d_in[13];
  const float* dk_w     = (const float*)d_in[14];
  const float* dk_b     = (const float*)d_in[15];
  const float* pv_w     = (const float*)d_in[16];
  const float* pv_b     = (const float*)d_in[17];
  const float* dv_w     = (const float*)d_in[18];
  const float* dv_b     = (const float*)d_in[19];
  const float* out_w    = (const float*)d_in[20];
  const float* out_b    = (const float*)d_in[21];
  const float* alpha    = (const float*)d_in[22];
  const float* lambd    = (const float*)d_in[23];
  const float* beta     = (const float*)d_in[24];

  u32* s = (u32*)d_ws;
  u32* S0 = s;             // FR  -> Q        (packed)
  u32* S1 = s + SLOT;      // FN  -> K        (packed)
  u32* S2 = s + 2 * SLOT;  // Fw  -> mix      (packed, in-place)
  u32* S3 = s + 3 * SLOT;  // Pq  -> Krev     (packed)
  u32* S4 = s + 4 * SLOT;  // Pk  -> V        (packed)
  u32* S5 = s + 5 * SLOT;  // Pv  -> S        (packed)
  float* Lp     = (float*)(s + 6 * SLOT);             // [8][SPLITK][256][256] fp32
  u32*   Lb     = (u32*)(Lp + (long)8 * SPLITK * 65536);  // packed attn weights
  float* pooled = (float*)(Lb + (long)8 * 65536);
  float* attn2  = pooled + 2048;
  u32*   wR     = (u32*)(attn2 + 4096);               // packed weights
  u32*   wN     = wR + 65536;
  u32*   wQ     = wN + 32768;
  u32*   wK     = wQ + 65536;
  u32*   wV     = wK + 65536;
  u32*   wO     = wV + 65536;

  const size_t needed =
      (size_t)(6 * SLOT + (long)8 * SPLITK * 65536 + 8L * 65536 + 2048 + 4096
               + 65536 * 5 + 32768) * 4;
  if (ws_size < needed) return;

  const long ST2 = (long)128 * HW;
  const long STL = (long)256 * 256;
  const dim3 gBig(32, 2, 8);

  // pre-split weights to packed format
  cvt_kernel<<<64, 256, 0, stream>>>(conv_r_w, wR, 16384);
  cvt_kernel<<<32, 256, 0, stream>>>(conv_n_w, wN, 8192);
  cvt_kernel<<<64, 256, 0, stream>>>(pq_w, wQ, 16384);
  cvt_kernel<<<64, 256, 0, stream>>>(pk_w, wK, 16384);
  cvt_kernel<<<64, 256, 0, stream>>>(pv_w, wV, 16384);
  cvt_kernel<<<64, 256, 0, stream>>>(out_w, wO, 16384);

  // FR = conv_r(x1), FN = conv_n(x2)   (B = fp32 inputs)
  gemm_mfma<false, 1><<<gBig, 256, 0, stream>>>(wR, x1, S0, conv_r_b,
      256, 0L, ST, ST, nullptr, nullptr, nullptr, nullptr, nullptr);
  gemm_mfma<false, 1><<<gBig, 256, 0, stream>>>(wN, x2, S1, conv_n_b,
      128, 0L, ST2, ST, nullptr, nullptr, nullptr, nullptr, nullptr);

  pool_kernel<<<2048, 256, 0, stream>>>(S0, S1, pooled);
  attn2_kernel<<<8, 256, 0, stream>>>(pooled, mlp_w1, mlp_w2, attn2);
  fw_kernel<<<dim3(4, 256, 8), 256, 0, stream>>>(S0, S1, attn2, S2);

  // Pq/Pk/Pv = 1x1 convs of Fw (packed B)
  gemm_mfma<true, 1><<<gBig, 256, 0, stream>>>(wQ, S2, S3, pq_b,
      256, 0L, ST, ST, nullptr, nullptr, nullptr, nullptr, nullptr);
  gemm_mfma<true, 1><<<gBig, 256, 0, stream>>>(wK, S2, S4, pk_b,
      256, 0L, ST, ST, nullptr, nullptr, nullptr, nullptr, nullptr);
  gemm_mfma<true, 1><<<gBig, 256, 0, stream>>>(wV, S2, S5, pv_b,
      256, 0L, ST, ST, nullptr, nullptr, nullptr, nullptr, nullptr);

  // depthwise 3x3 (packed in/out)
  dw_kernel<<<2048, 256, 0, stream>>>(S3, dq_w, dq_b, S0, nullptr);  // Q  -> S0
  dw_kernel<<<2048, 256, 0, stream>>>(S4, dk_w, dk_b, S1, S3);       // K  -> S1, Krev -> S3
  dw_kernel<<<2048, 256, 0, stream>>>(S5, dv_w, dv_b, S4, nullptr);  // V  -> S4

  // S = circconv2(Q, K)
  sconv_kernel<<<2048, 256, 0, stream>>>(S0, S1, S5);                // S -> S5

  // attn logits via MFMA split-K, then fused reduce+softmax (packed Lb)
  gemm_logits<<<dim3(2, 2, 64), 256, 0, stream>>>(S0, S3, Lp);
  softmax_kernel<<<2048, 256, 0, stream>>>(Lp, Lb, alpha);

  // cfr = attn_w @ S, fused mix epilogue (packed, in-place into S2)
  gemm_mfma<true, 2><<<gBig, 256, 0, stream>>>(Lb, S5, S2, nullptr,
      256, STL, ST, ST, S0, S4, S2, lambd, beta);

  // final 1x1 conv -> d_out (fp32 + bias)
  gemm_mfma<true, 0><<<gBig, 256, 0, stream>>>(wO, S2, d_out, out_b,
      256, 0L, ST, ST, nullptr, nullptr, nullptr, nullptr, nullptr);
}